// Round 2
// baseline (1769.797 us; speedup 1.0000x reference)
//
#include <hip/hip_runtime.h>
#include <hip/hip_bf16.h>

#define Bn 32
#define Dd 256
#define Tt 1024
#define Nn (Bn * Tt)   // 32768
#define Kk 8192

// ---------------- kernel 0: transpose W [K][D] -> Wt [D][K] in ws ----------------
__global__ void k_transpose(const float* __restrict__ w, float* __restrict__ wtg) {
    __shared__ float tile[32][33];
    const int k0 = blockIdx.x * 32;
    const int d0 = blockIdx.y * 32;
    const int tx = threadIdx.x, ty = threadIdx.y;
#pragma unroll
    for (int r = 0; r < 32; r += 8)
        tile[r + ty][tx] = w[(size_t)(k0 + r + ty) * Dd + d0 + tx];
    __syncthreads();
#pragma unroll
    for (int r = 0; r < 32; r += 8)
        wtg[(size_t)(d0 + r + ty) * Kk + k0 + tx] = tile[tx][r + ty];
}

// ---------------- kernel 1: numpy-pairwise-exact sum of squares ----------------
// Replicates np.sum(a*a, axis=1) for 256-elem contiguous rows:
// n=256 -> pairwise(128)+pairwise(128); each 128-block: 8 accumulators,
// r[j] = a[j] + a[8+j] + ... (15 sequential adds), combine
// ((r0+r1)+(r2+r3))+((r4+r5)+(r6+r7)). Squares round separately (contract off).
__global__ void k_sumx2_np(const float* __restrict__ x, float* __restrict__ c) {
#pragma clang fp contract(off)
    const int n = blockIdx.x * 256 + threadIdx.x;
    const int b = n >> 10, t = n & 1023;
    const float* p = x + (size_t)b * (Dd * Tt) + t;
    float h[2];
#pragma unroll
    for (int half = 0; half < 2; ++half) {
        float r[8];
#pragma unroll
        for (int j = 0; j < 8; ++j) {
            const float v = p[(size_t)(half * 128 + j) * Tt];
            const float sq = v * v;
            r[j] = sq;
        }
        for (int i = 8; i < 128; i += 8) {
#pragma unroll
            for (int j = 0; j < 8; ++j) {
                const float v = p[(size_t)(half * 128 + i + j) * Tt];
                const float sq = v * v;
                r[j] = r[j] + sq;
            }
        }
        h[half] = ((r[0] + r[1]) + (r[2] + r[3])) + ((r[4] + r[5]) + (r[6] + r[7]));
    }
    c[n] = h[0] + h[1];
}

__global__ void k_sumw2_np(const float* __restrict__ w, float* __restrict__ sw) {
#pragma clang fp contract(off)
    const int k = blockIdx.x * 256 + threadIdx.x;
    const float* p = w + (size_t)k * Dd;
    float h[2];
#pragma unroll
    for (int half = 0; half < 2; ++half) {
        float r[8];
#pragma unroll
        for (int j = 0; j < 8; ++j) {
            const float v = p[half * 128 + j];
            const float sq = v * v;
            r[j] = sq;
        }
        for (int i = 8; i < 128; i += 8) {
#pragma unroll
            for (int j = 0; j < 8; ++j) {
                const float v = p[half * 128 + i + j];
                const float sq = v * v;
                r[j] = r[j] + sq;
            }
        }
        h[half] = ((r[0] + r[1]) + (r[2] + r[3])) + ((r[4] + r[5]) + (r[6] + r[7]));
    }
    sw[k] = h[0] + h[1];
}

// ---------------- kernel 2: fused GEMM + argmin (np-f32 rounding replica) -------
// distances replicated as: t1 = fl32(C_n + sw2_k); s = fl32(t1 - 2*dot).
// grid 256 blocks (128 rows each), 512 threads, 8x8 thread tile.
template <bool WTG>
__global__ void __launch_bounds__(512, 2)
k_argmin(const float* __restrict__ x, const float* __restrict__ w,
         const float* __restrict__ wtg, const float* __restrict__ sw2,
         const float* __restrict__ cn,
         int* __restrict__ idx_out, float* __restrict__ idx_f) {
    __shared__ __align__(16) float At[32][132];   // [d][n] slice
    __shared__ __align__(16) float Wt[32][268];   // [d][k] slice
    const int tid = threadIdx.x;
    const int n0 = blockIdx.x * 128;
    const int b = n0 >> 10;
    const int t0 = n0 & 1023;
    const int ty = tid >> 5;    // 0..15
    const int tx = tid & 31;    // 0..31
    const int r0 = ty * 4;
    const int c0 = tx * 4;
    const float* xb = x + (size_t)b * (Dd * Tt) + t0;

    float c8[8];
#pragma unroll
    for (int i = 0; i < 8; ++i) {
        const int row = (i < 4) ? (r0 + i) : (64 + r0 + (i - 4));
        c8[i] = cn[n0 + row];
    }

    float best[8];
    int bidx[8];
#pragma unroll
    for (int i = 0; i < 8; ++i) { best[i] = 3.402823466e+38f; bidx[i] = 0; }

    for (int kc = 0; kc < Kk; kc += 256) {
        float acc[8][8];
#pragma unroll
        for (int i = 0; i < 8; ++i)
#pragma unroll
            for (int j = 0; j < 8; ++j) acc[i][j] = 0.0f;

        for (int ds = 0; ds < Dd; ds += 32) {
#pragma unroll
            for (int u = 0; u < 2; ++u) {
                int c = tid + 512 * u;          // 0..1023 ; 32 float4 per row
                int dd = c >> 5, i4 = c & 31;
                float4 v = *reinterpret_cast<const float4*>(
                    &xb[(size_t)(ds + dd) * Tt + i4 * 4]);
                *reinterpret_cast<float4*>(&At[dd][i4 * 4]) = v;
            }
            if (WTG) {
#pragma unroll
                for (int u = 0; u < 4; ++u) {
                    int c = tid + 512 * u;      // 0..2047 ; 64 float4 per row
                    int dd = c >> 6, j4 = c & 63;
                    float4 v = *reinterpret_cast<const float4*>(
                        &wtg[(size_t)(ds + dd) * Kk + kc + j4 * 4]);
                    *reinterpret_cast<float4*>(&Wt[dd][j4 * 4]) = v;
                }
            } else {
#pragma unroll
                for (int u = 0; u < 4; ++u) {
                    int c = tid + 512 * u;      // 0..2047: 256 j x 8 d-quads
                    int j = c >> 3, m = c & 7;
                    float4 v = *reinterpret_cast<const float4*>(
                        &w[(size_t)(kc + j) * Dd + ds + m * 4]);
                    Wt[m * 4 + 0][j] = v.x;
                    Wt[m * 4 + 1][j] = v.y;
                    Wt[m * 4 + 2][j] = v.z;
                    Wt[m * 4 + 3][j] = v.w;
                }
            }
            __syncthreads();
#pragma unroll 8
            for (int dd = 0; dd < 32; ++dd) {
                float4 a0 = *reinterpret_cast<const float4*>(&At[dd][r0]);
                float4 a1 = *reinterpret_cast<const float4*>(&At[dd][64 + r0]);
                float4 b0 = *reinterpret_cast<const float4*>(&Wt[dd][c0]);
                float4 b1 = *reinterpret_cast<const float4*>(&Wt[dd][128 + c0]);
                float av[8] = {a0.x, a0.y, a0.z, a0.w, a1.x, a1.y, a1.z, a1.w};
                float bv[8] = {b0.x, b0.y, b0.z, b0.w, b1.x, b1.y, b1.z, b1.w};
#pragma unroll
                for (int i = 0; i < 8; ++i)
#pragma unroll
                    for (int j = 0; j < 8; ++j)
                        acc[i][j] = fmaf(av[i], bv[j], acc[i][j]);
            }
            __syncthreads();
        }
        // fold this 256-code chunk into the running argmin, np-f32 rounding
#pragma unroll
        for (int j = 0; j < 8; ++j) {
            const int col = (j < 4) ? (c0 + j) : (128 + c0 + (j - 4));
            const int k = kc + col;
            const float sw = sw2[k];
#pragma unroll
            for (int i = 0; i < 8; ++i) {
                const float t1 = c8[i] + sw;               // fl32(C_n + sw2_k)
                const float s = fmaf(-2.0f, acc[i][j], t1); // fl32(t1 - 2*dot), exact 2x
                if (s < best[i] || (s == best[i] && k < bidx[i])) {
                    best[i] = s; bidx[i] = k;
                }
            }
        }
    }
#pragma unroll
    for (int i = 0; i < 8; ++i) {
        float v = best[i];
        int id = bidx[i];
#pragma unroll
        for (int m = 1; m < 32; m <<= 1) {
            const float ov = __shfl_xor(v, m);
            const int oi = __shfl_xor(id, m);
            if (ov < v || (ov == v && oi < id)) { v = ov; id = oi; }
        }
        if (tx == 0) {
            const int row = (i < 4) ? (r0 + i) : (64 + r0 + (i - 4));
            const int n = n0 + row;
            idx_out[n] = id;
            idx_f[n] = (float)id;
        }
    }
}

// ---------------- kernel 3: gather + STE write-back + partial loss ----------------
__global__ void k_quant(const float* __restrict__ x, const float* __restrict__ w,
                        const int* __restrict__ idx, float* __restrict__ outq,
                        double* __restrict__ part) {
#pragma clang fp contract(off)
    __shared__ double red[256];
    const int tid = threadIdx.x;
    const int n0 = blockIdx.x * 64;
    const int b = n0 >> 10, t0 = n0 & 1023;
    const int tl = tid & 63;
    const int d0 = tid >> 6;
    const int n = n0 + tl;
    const int code = idx[n];
    const float* wr = w + (size_t)code * Dd;
    const size_t base = (size_t)b * (Dd * Tt) + t0 + tl;
    double s = 0.0;
    for (int d = d0; d < Dd; d += 4) {
        const float xv = x[base + (size_t)d * Tt];
        const float qv = wr[d];
        const float d1 = qv - xv;      // fl(q - x)
        const float qs = xv + d1;      // fl(x + (q-x)) = straight-through value
        const float d2 = qs - xv;      // fl(qs - x) loss term
        s += (double)d2 * (double)d2;
        outq[base + (size_t)d * Tt] = qs;
    }
    red[tid] = s;
    __syncthreads();
    for (int st = 128; st > 0; st >>= 1) {
        if (tid < st) red[tid] += red[tid + st];
        __syncthreads();
    }
    if (tid == 0) part[blockIdx.x] = red[0];
}

// ---------------- kernel 4: final loss ----------------
__global__ void k_loss(const double* __restrict__ part, float* __restrict__ loss) {
    __shared__ double red[512];
    const int tid = threadIdx.x;
    red[tid] = part[tid];
    __syncthreads();
    for (int st = 256; st > 0; st >>= 1) {
        if (tid < st) red[tid] += red[tid + st];
        __syncthreads();
    }
    if (tid == 0)
        loss[0] = (float)(1.25 * red[0] / (double)((size_t)Bn * Dd * Tt));
}

extern "C" void kernel_launch(void* const* d_in, const int* in_sizes, int n_in,
                              void* d_out, int out_size, void* d_ws, size_t ws_size,
                              hipStream_t stream) {
    const float* x = (const float*)d_in[0];   // [32][256][1024] f32
    const float* w = (const float*)d_in[1];   // [8192][256] f32
    float* out = (float*)d_out;
    float* loss = out;
    float* outq = out + 1;
    float* idxf = out + 1 + (size_t)Bn * Dd * Tt;

    char* ws = (char*)d_ws;
    float* sw2 = (float*)(ws);                  // 8192 f32   @ 0
    int* idx = (int*)(ws + 32768);              // 32768 i32  @ 32KB
    double* part = (double*)(ws + 163840);      // 512 f64    @ 160KB
    float* cn = (float*)(ws + 172032);          // 32768 f32  @ 168KB
    float* wtg = (float*)(ws + 524288);         // 8 MB       @ 512KB
    const bool use_wtg = ws_size >= (size_t)524288 + (size_t)Kk * Dd * 4;

    if (use_wtg)
        k_transpose<<<dim3(Kk / 32, Dd / 32), dim3(32, 8), 0, stream>>>(w, wtg);
    k_sumx2_np<<<Nn / 256, 256, 0, stream>>>(x, cn);
    k_sumw2_np<<<Kk / 256, 256, 0, stream>>>(w, sw2);
    if (use_wtg)
        k_argmin<true><<<Nn / 128, 512, 0, stream>>>(x, w, wtg, sw2, cn, idx, idxf);
    else
        k_argmin<false><<<Nn / 128, 512, 0, stream>>>(x, w, wtg, sw2, cn, idx, idxf);
    k_quant<<<Nn / 64, 256, 0, stream>>>(x, w, idx, outq, part);
    k_loss<<<1, 512, 0, stream>>>(part, loss);
}

// Round 4
// 958.161 us; speedup vs baseline: 1.8471x; 1.8471x over previous
//
#include <hip/hip_runtime.h>
#include <hip/hip_bf16.h>

#define Bn 32
#define Dd 256
#define Tt 1024
#define Nn (Bn * Tt)   // 32768
#define Kk 8192

typedef __attribute__((ext_vector_type(8))) short bf16x8;
typedef __attribute__((ext_vector_type(4))) float f32x4;

static __device__ __forceinline__ short f2bf(float v) {
    __hip_bfloat16 h = __float2bfloat16(v);
    return *reinterpret_cast<short*>(&h);
}

// ===================== NEW PATH =====================
// ws layout (bytes):
#define OFF_XT   0ULL            // f32 [32768][256]  32 MB
#define OFF_WT   33554432ULL     // f32 [256][8192]    8 MB
#define OFF_XBT  41943040ULL     // bf16 [32768][256] 16 MB
#define OFF_WBT  58720256ULL     // bf16 [8192][256]   4 MB
#define OFF_CMIN 62914560ULL     // f32 [32768][64]    8 MB
#define OFF_LIST 71303168ULL     // u16 [64][32768]    4 MB
#define OFF_KEYS 75497472ULL     // u64 [32768]      256 KB
#define OFF_SW2  75759616ULL     // f32 [8192]
#define OFF_CN   75792384ULL     // f32 [32768]
#define OFF_CNT  75923456ULL     // u32 [64]
#define OFF_PART 75923712ULL     // f64 [512]
#define WS_NEED  75927808ULL

// ---- prep: x [b][d][t] -> xT f32 [n][d], xbt bf16 [n][d] ----
__global__ void k_xprep(const float* __restrict__ x, float* __restrict__ xT,
                        short* __restrict__ xbt) {
    __shared__ float tile[32][33];
    const int b = blockIdx.z, d0 = blockIdx.y * 32, t0 = blockIdx.x * 32;
    const int tx = threadIdx.x, ty = threadIdx.y;
#pragma unroll
    for (int r = 0; r < 32; r += 8)
        tile[ty + r][tx] = x[((size_t)(b * Dd + d0 + ty + r)) * Tt + t0 + tx];
    __syncthreads();
#pragma unroll
    for (int r = 0; r < 32; r += 8) {
        const size_t o = (size_t)(b * Tt + t0 + ty + r) * Dd + d0 + tx;
        const float v = tile[tx][ty + r];
        xT[o] = v;
        xbt[o] = f2bf(v);
    }
}

// ---- prep: w [k][d] -> wT f32 [d][k], wbt bf16 [k][d] ----
__global__ void k_wprep(const float* __restrict__ w, float* __restrict__ wT,
                        short* __restrict__ wbt) {
    __shared__ float tile[32][33];
    const int k0 = blockIdx.x * 32, d0 = blockIdx.y * 32;
    const int tx = threadIdx.x, ty = threadIdx.y;
#pragma unroll
    for (int r = 0; r < 32; r += 8) {
        const float v = w[(size_t)(k0 + r + ty) * Dd + d0 + tx];
        tile[r + ty][tx] = v;
        wbt[(size_t)(k0 + r + ty) * Dd + d0 + tx] = f2bf(v);
    }
    __syncthreads();
#pragma unroll
    for (int r = 0; r < 32; r += 8)
        wT[(size_t)(d0 + r + ty) * Kk + k0 + tx] = tile[tx][r + ty];
}

// ---- numpy-pairwise-exact sum of squares (proven in round 2) ----
__global__ void k_sumx2_np(const float* __restrict__ x, float* __restrict__ c) {
#pragma clang fp contract(off)
    const int n = blockIdx.x * 256 + threadIdx.x;
    const int b = n >> 10, t = n & 1023;
    const float* p = x + (size_t)b * (Dd * Tt) + t;
    float h[2];
#pragma unroll
    for (int half = 0; half < 2; ++half) {
        float r[8];
#pragma unroll
        for (int j = 0; j < 8; ++j) {
            const float v = p[(size_t)(half * 128 + j) * Tt];
            r[j] = v * v;
        }
        for (int i = 8; i < 128; i += 8) {
#pragma unroll
            for (int j = 0; j < 8; ++j) {
                const float v = p[(size_t)(half * 128 + i + j) * Tt];
                const float sq = v * v;
                r[j] = r[j] + sq;
            }
        }
        h[half] = ((r[0] + r[1]) + (r[2] + r[3])) + ((r[4] + r[5]) + (r[6] + r[7]));
    }
    c[n] = h[0] + h[1];
}

__global__ void k_sumw2_np(const float* __restrict__ w, float* __restrict__ sw) {
#pragma clang fp contract(off)
    const int k = blockIdx.x * 256 + threadIdx.x;
    const float* p = w + (size_t)k * Dd;
    float h[2];
#pragma unroll
    for (int half = 0; half < 2; ++half) {
        float r[8];
#pragma unroll
        for (int j = 0; j < 8; ++j) {
            const float v = p[half * 128 + j];
            r[j] = v * v;
        }
        for (int i = 8; i < 128; i += 8) {
#pragma unroll
            for (int j = 0; j < 8; ++j) {
                const float v = p[half * 128 + i + j];
                const float sq = v * v;
                r[j] = r[j] + sq;
            }
        }
        h[half] = ((r[0] + r[1]) + (r[2] + r[3])) + ((r[4] + r[5]) + (r[6] + r[7]));
    }
    sw[k] = h[0] + h[1];
}

// ---- stage 1: bf16 MFMA approx distances, per-(row,chunk) minima ----
// 8 waves, wave-tile 16 rows x 128 codes (1x8 tiles of 16x16).
// Each row's chunk-min lives entirely in ONE wave (fixes round-3 race).
__global__ void __launch_bounds__(512, 1)
k_mfma_filter(const short* __restrict__ xbt, const short* __restrict__ wbt,
              const float* __restrict__ sw2, float* __restrict__ cmin) {
    __shared__ __align__(16) short As[128 * 264];
    __shared__ __align__(16) short Ws[128 * 264];
    const int tid = threadIdx.x;
    const int n0 = blockIdx.x * 128;
    const int wid = tid >> 6, lane = tid & 63;
    const int l15 = lane & 15, l4 = lane >> 4;

    // stage A once: rows n0..n0+127, all 256 d
#pragma unroll
    for (int m = 0; m < 16; ++m) {
        const int e = tid + 512 * m;          // 0..8191
        const int row = e >> 6, d4 = e & 63;
        const short4 v = *reinterpret_cast<const short4*>(
            &xbt[(size_t)(n0 + row) * Dd + d4 * 4]);
        *reinterpret_cast<short4*>(&As[row * 264 + d4 * 4]) = v;
    }
    __syncthreads();

    for (int c = 0; c < 64; ++c) {
        // stage W chunk: codes 128c..128c+127
#pragma unroll
        for (int m = 0; m < 16; ++m) {
            const int e = tid + 512 * m;
            const int code = e >> 6, d4 = e & 63;
            const short4 v = *reinterpret_cast<const short4*>(
                &wbt[(size_t)(128 * c + code) * Dd + d4 * 4]);
            *reinterpret_cast<short4*>(&Ws[code * 264 + d4 * 4]) = v;
        }
        __syncthreads();

        f32x4 acc[8];
#pragma unroll
        for (int ct = 0; ct < 8; ++ct) acc[ct] = (f32x4)0.0f;

#pragma unroll
        for (int ks = 0; ks < 8; ++ks) {
            const bf16x8 a = *reinterpret_cast<const bf16x8*>(
                &As[(16 * wid + l15) * 264 + ks * 32 + 8 * l4]);
#pragma unroll
            for (int ct = 0; ct < 8; ++ct) {
                const bf16x8 b = *reinterpret_cast<const bf16x8*>(
                    &Ws[(16 * ct + l15) * 264 + ks * 32 + 8 * l4]);
                acc[ct] = __builtin_amdgcn_mfma_f32_16x16x32_bf16(a, b, acc[ct], 0, 0, 0);
            }
        }
        __syncthreads();   // LDS reads done; next chunk may restage

        // epilogue: u = sw - 2*dot ; per-row chunk-min (within one wave)
        float swc[8];
#pragma unroll
        for (int ct = 0; ct < 8; ++ct)
            swc[ct] = sw2[128 * c + 16 * ct + l15];
#pragma unroll
        for (int r = 0; r < 4; ++r) {
            float mm = fmaf(-2.0f, acc[0][r], swc[0]);
#pragma unroll
            for (int ct = 1; ct < 8; ++ct)
                mm = fminf(mm, fmaf(-2.0f, acc[ct][r], swc[ct]));
#pragma unroll
            for (int d = 1; d < 16; d <<= 1)
                mm = fminf(mm, __shfl_xor(mm, d));
            if (l15 == 0) {
                const int row = n0 + 16 * wid + 4 * l4 + r;   // C/D: row=(lane>>4)*4+reg
                cmin[(size_t)row * 64 + c] = mm;
            }
        }
    }
}

// ---- select: margin filter -> per-chunk row lists; init keys ----
__global__ void k_select(const float* __restrict__ cmin, const float* __restrict__ cn,
                         unsigned long long* __restrict__ keys,
                         unsigned int* __restrict__ cnt, unsigned short* __restrict__ lists) {
    const int n = blockIdx.x * 256 + threadIdx.x;
    float gmin = 3.402823466e+38f;
#pragma unroll
    for (int c4 = 0; c4 < 16; ++c4) {
        const float4 v = *reinterpret_cast<const float4*>(&cmin[(size_t)n * 64 + c4 * 4]);
        gmin = fminf(gmin, fminf(fminf(v.x, v.y), fminf(v.z, v.w)));
    }
    keys[n] = 0xFFFFFFFFFFFFFFFFULL;
    const float margin = 7.1e-5f + 2.6e-5f * sqrtf(cn[n]);
    const float thr = gmin + margin;
    for (int c = 0; c < 64; ++c) {
        if (cmin[(size_t)n * 64 + c] <= thr) {
            const unsigned int pos = atomicAdd(&cnt[c], 1u);
            lists[(size_t)c * Nn + pos] = (unsigned short)n;
        }
    }
}

// ---- refine: exact f32 recompute (bit-identical to round-2 chain) ----
__global__ void __launch_bounds__(256, 1)
k_refine(const float* __restrict__ xT, const float* __restrict__ wT,
         const float* __restrict__ sw2, const float* __restrict__ cn,
         const unsigned int* __restrict__ cnt, const unsigned short* __restrict__ lists,
         unsigned long long* __restrict__ keys) {
    __shared__ __align__(16) float xs[64 * 260];
    __shared__ float sm[64 * 130];
    __shared__ float cns[64];
    __shared__ unsigned short rid_s[64];
    const int c = blockIdx.x, gb = blockIdx.y;
    const int tid = threadIdx.x;
    const int cntc = (int)cnt[c];
    const int kl = tid & 127, rg = tid >> 7;
    const int kg = 128 * c + kl;
    const float swk = sw2[kg];

    for (int start = gb * 64; start < cntc; start += 8 * 64) {
#pragma unroll
        for (int m = 0; m < 16; ++m) {
            const int e = tid + 256 * m;      // 0..4095
            const int j = e >> 6, d4 = e & 63;
            const int li = min(start + j, cntc - 1);
            const int row = lists[(size_t)c * Nn + li];
            const float4 v = *reinterpret_cast<const float4*>(&xT[(size_t)row * Dd + d4 * 4]);
            *reinterpret_cast<float4*>(&xs[j * 260 + d4 * 4]) = v;
        }
        if (tid < 64) {
            const int li = min(start + tid, cntc - 1);
            const unsigned short row = lists[(size_t)c * Nn + li];
            rid_s[tid] = row;
            cns[tid] = cn[row];
        }
        __syncthreads();

        float acc[32];
#pragma unroll
        for (int r = 0; r < 32; ++r) acc[r] = 0.0f;
        for (int d4 = 0; d4 < 64; ++d4) {
            const float w0 = wT[(size_t)(d4 * 4 + 0) * Kk + kg];
            const float w1 = wT[(size_t)(d4 * 4 + 1) * Kk + kg];
            const float w2 = wT[(size_t)(d4 * 4 + 2) * Kk + kg];
            const float w3 = wT[(size_t)(d4 * 4 + 3) * Kk + kg];
#pragma unroll
            for (int r = 0; r < 32; ++r) {
                const float4 xv = *reinterpret_cast<const float4*>(
                    &xs[(rg * 32 + r) * 260 + d4 * 4]);
                acc[r] = fmaf(xv.x, w0, acc[r]);
                acc[r] = fmaf(xv.y, w1, acc[r]);
                acc[r] = fmaf(xv.z, w2, acc[r]);
                acc[r] = fmaf(xv.w, w3, acc[r]);
            }
        }
#pragma unroll
        for (int r = 0; r < 32; ++r) {
            const float t1 = cns[rg * 32 + r] + swk;        // fl32(cn + sw)
            sm[(rg * 32 + r) * 130 + kl] = fmaf(-2.0f, acc[r], t1);
        }
        __syncthreads();

        {
            const int r = tid >> 2, q = tid & 3;
            float bv = 3.402823466e+38f;
            int bk = 0x7FFFFFFF;
            for (int u = 0; u < 32; ++u) {
                const int kloc = q * 32 + u;
                const float s = sm[r * 130 + kloc];
                const int k = 128 * c + kloc;
                if (s < bv || (s == bv && k < bk)) { bv = s; bk = k; }
            }
#pragma unroll
            for (int d = 1; d < 4; d <<= 1) {
                const float ov = __shfl_xor(bv, d);
                const int ok = __shfl_xor(bk, d);
                if (ov < bv || (ov == bv && ok < bk)) { bv = ov; bk = ok; }
            }
            if (q == 0) {
                unsigned int sb = __float_as_uint(bv);
                const unsigned long long key = ((unsigned long long)sb << 32) |
                                               (unsigned long long)(unsigned int)bk;
                atomicMin(&keys[rid_s[r]], key);
            }
        }
        __syncthreads();
    }
}

// ---- gather + STE + partial loss (round-2 proven, key-indexed) ----
__global__ void k_quant2(const float* __restrict__ x, const float* __restrict__ w,
                         const unsigned long long* __restrict__ keys,
                         float* __restrict__ outq, float* __restrict__ idxf,
                         double* __restrict__ part) {
#pragma clang fp contract(off)
    __shared__ double red[256];
    const int tid = threadIdx.x;
    const int n0 = blockIdx.x * 64;
    const int b = n0 >> 10, t0 = n0 & 1023;
    const int tl = tid & 63;
    const int d0 = tid >> 6;
    const int n = n0 + tl;
    const int code = (int)(unsigned int)(keys[n] & 0xFFFFFFFFULL);
    if (tid < 64) idxf[n0 + tid] = (float)(int)(unsigned int)(keys[n0 + tid] & 0xFFFFFFFFULL);
    const float* wr = w + (size_t)code * Dd;
    const size_t base = (size_t)b * (Dd * Tt) + t0 + tl;
    double s = 0.0;
    for (int d = d0; d < Dd; d += 4) {
        const float xv = x[base + (size_t)d * Tt];
        const float qv = wr[d];
        const float d1 = qv - xv;
        const float qs = xv + d1;
        const float d2 = qs - xv;
        s += (double)d2 * (double)d2;
        outq[base + (size_t)d * Tt] = qs;
    }
    red[tid] = s;
    __syncthreads();
    for (int st = 128; st > 0; st >>= 1) {
        if (tid < st) red[tid] += red[tid + st];
        __syncthreads();
    }
    if (tid == 0) part[blockIdx.x] = red[0];
}

__global__ void k_loss(const double* __restrict__ part, float* __restrict__ loss) {
    __shared__ double red[512];
    const int tid = threadIdx.x;
    red[tid] = part[tid];
    __syncthreads();
    for (int st = 256; st > 0; st >>= 1) {
        if (tid < st) red[tid] += red[tid + st];
        __syncthreads();
    }
    if (tid == 0)
        loss[0] = (float)(1.25 * red[0] / (double)((size_t)Bn * Dd * Tt));
}

// ===================== LEGACY (round-2 proven) FALLBACK =====================
__global__ void k_transpose(const float* __restrict__ w, float* __restrict__ wtg) {
    __shared__ float tile[32][33];
    const int k0 = blockIdx.x * 32;
    const int d0 = blockIdx.y * 32;
    const int tx = threadIdx.x, ty = threadIdx.y;
#pragma unroll
    for (int r = 0; r < 32; r += 8)
        tile[r + ty][tx] = w[(size_t)(k0 + r + ty) * Dd + d0 + tx];
    __syncthreads();
#pragma unroll
    for (int r = 0; r < 32; r += 8)
        wtg[(size_t)(d0 + r + ty) * Kk + k0 + tx] = tile[tx][r + ty];
}

template <bool WTG>
__global__ void __launch_bounds__(512, 2)
k_argmin(const float* __restrict__ x, const float* __restrict__ w,
         const float* __restrict__ wtg, const float* __restrict__ sw2,
         const float* __restrict__ cn,
         int* __restrict__ idx_out, float* __restrict__ idx_f) {
    __shared__ __align__(16) float At[32][132];
    __shared__ __align__(16) float Wt[32][268];
    const int tid = threadIdx.x;
    const int n0 = blockIdx.x * 128;
    const int b = n0 >> 10;
    const int t0 = n0 & 1023;
    const int ty = tid >> 5;
    const int tx = tid & 31;
    const int r0 = ty * 4;
    const int c0 = tx * 4;
    const float* xb = x + (size_t)b * (Dd * Tt) + t0;

    float c8[8];
#pragma unroll
    for (int i = 0; i < 8; ++i) {
        const int row = (i < 4) ? (r0 + i) : (64 + r0 + (i - 4));
        c8[i] = cn[n0 + row];
    }
    float best[8];
    int bidx[8];
#pragma unroll
    for (int i = 0; i < 8; ++i) { best[i] = 3.402823466e+38f; bidx[i] = 0; }

    for (int kc = 0; kc < Kk; kc += 256) {
        float acc[8][8];
#pragma unroll
        for (int i = 0; i < 8; ++i)
#pragma unroll
            for (int j = 0; j < 8; ++j) acc[i][j] = 0.0f;
        for (int ds = 0; ds < Dd; ds += 32) {
#pragma unroll
            for (int u = 0; u < 2; ++u) {
                int cc = tid + 512 * u;
                int dd = cc >> 5, i4 = cc & 31;
                float4 v = *reinterpret_cast<const float4*>(
                    &xb[(size_t)(ds + dd) * Tt + i4 * 4]);
                *reinterpret_cast<float4*>(&At[dd][i4 * 4]) = v;
            }
            if (WTG) {
#pragma unroll
                for (int u = 0; u < 4; ++u) {
                    int cc = tid + 512 * u;
                    int dd = cc >> 6, j4 = cc & 63;
                    float4 v = *reinterpret_cast<const float4*>(
                        &wtg[(size_t)(ds + dd) * Kk + kc + j4 * 4]);
                    *reinterpret_cast<float4*>(&Wt[dd][j4 * 4]) = v;
                }
            } else {
#pragma unroll
                for (int u = 0; u < 4; ++u) {
                    int cc = tid + 512 * u;
                    int j = cc >> 3, m = cc & 7;
                    float4 v = *reinterpret_cast<const float4*>(
                        &w[(size_t)(kc + j) * Dd + ds + m * 4]);
                    Wt[m * 4 + 0][j] = v.x;
                    Wt[m * 4 + 1][j] = v.y;
                    Wt[m * 4 + 2][j] = v.z;
                    Wt[m * 4 + 3][j] = v.w;
                }
            }
            __syncthreads();
#pragma unroll 8
            for (int dd = 0; dd < 32; ++dd) {
                float4 a0 = *reinterpret_cast<const float4*>(&At[dd][r0]);
                float4 a1 = *reinterpret_cast<const float4*>(&At[dd][64 + r0]);
                float4 b0 = *reinterpret_cast<const float4*>(&Wt[dd][c0]);
                float4 b1 = *reinterpret_cast<const float4*>(&Wt[dd][128 + c0]);
                float av[8] = {a0.x, a0.y, a0.z, a0.w, a1.x, a1.y, a1.z, a1.w};
                float bv[8] = {b0.x, b0.y, b0.z, b0.w, b1.x, b1.y, b1.z, b1.w};
#pragma unroll
                for (int i = 0; i < 8; ++i)
#pragma unroll
                    for (int j = 0; j < 8; ++j)
                        acc[i][j] = fmaf(av[i], bv[j], acc[i][j]);
            }
            __syncthreads();
        }
#pragma unroll
        for (int j = 0; j < 8; ++j) {
            const int col = (j < 4) ? (c0 + j) : (128 + c0 + (j - 4));
            const int k = kc + col;
            const float sw = sw2[k];
#pragma unroll
            for (int i = 0; i < 8; ++i) {
                const float t1 = c8[i] + sw;
                const float s = fmaf(-2.0f, acc[i][j], t1);
                if (s < best[i] || (s == best[i] && k < bidx[i])) {
                    best[i] = s; bidx[i] = k;
                }
            }
        }
    }
#pragma unroll
    for (int i = 0; i < 8; ++i) {
        float v = best[i];
        int id = bidx[i];
#pragma unroll
        for (int m = 1; m < 32; m <<= 1) {
            const float ov = __shfl_xor(v, m);
            const int oi = __shfl_xor(id, m);
            if (ov < v || (ov == v && oi < id)) { v = ov; id = oi; }
        }
        if (tx == 0) {
            const int row = (i < 4) ? (r0 + i) : (64 + r0 + (i - 4));
            const int n = n0 + row;
            idx_out[n] = id;
            idx_f[n] = (float)id;
        }
    }
}

__global__ void k_quant(const float* __restrict__ x, const float* __restrict__ w,
                        const int* __restrict__ idx, float* __restrict__ outq,
                        double* __restrict__ part) {
#pragma clang fp contract(off)
    __shared__ double red[256];
    const int tid = threadIdx.x;
    const int n0 = blockIdx.x * 64;
    const int b = n0 >> 10, t0 = n0 & 1023;
    const int tl = tid & 63;
    const int d0 = tid >> 6;
    const int n = n0 + tl;
    const int code = idx[n];
    const float* wr = w + (size_t)code * Dd;
    const size_t base = (size_t)b * (Dd * Tt) + t0 + tl;
    double s = 0.0;
    for (int d = d0; d < Dd; d += 4) {
        const float xv = x[base + (size_t)d * Tt];
        const float qv = wr[d];
        const float d1 = qv - xv;
        const float qs = xv + d1;
        const float d2 = qs - xv;
        s += (double)d2 * (double)d2;
        outq[base + (size_t)d * Tt] = qs;
    }
    red[tid] = s;
    __syncthreads();
    for (int st = 128; st > 0; st >>= 1) {
        if (tid < st) red[tid] += red[tid + st];
        __syncthreads();
    }
    if (tid == 0) part[blockIdx.x] = red[0];
}

// ===================== host =====================
extern "C" void kernel_launch(void* const* d_in, const int* in_sizes, int n_in,
                              void* d_out, int out_size, void* d_ws, size_t ws_size,
                              hipStream_t stream) {
    const float* x = (const float*)d_in[0];
    const float* w = (const float*)d_in[1];
    float* out = (float*)d_out;
    float* loss = out;
    float* outq = out + 1;
    float* idxf = out + 1 + (size_t)Bn * Dd * Tt;
    char* ws = (char*)d_ws;

    if (ws_size >= WS_NEED) {
        float* xT = (float*)(ws + OFF_XT);
        float* wT = (float*)(ws + OFF_WT);
        short* xbt = (short*)(ws + OFF_XBT);
        short* wbt = (short*)(ws + OFF_WBT);
        float* cmin = (float*)(ws + OFF_CMIN);
        unsigned short* lists = (unsigned short*)(ws + OFF_LIST);
        unsigned long long* keys = (unsigned long long*)(ws + OFF_KEYS);
        float* sw2 = (float*)(ws + OFF_SW2);
        float* cn = (float*)(ws + OFF_CN);
        unsigned int* cnt = (unsigned int*)(ws + OFF_CNT);
        double* part = (double*)(ws + OFF_PART);

        hipMemsetAsync(cnt, 0, 64 * sizeof(unsigned int), stream);
        k_xprep<<<dim3(32, 8, 32), dim3(32, 8), 0, stream>>>(x, xT, xbt);
        k_wprep<<<dim3(256, 8), dim3(32, 8), 0, stream>>>(w, wT, wbt);
        k_sumx2_np<<<Nn / 256, 256, 0, stream>>>(x, cn);
        k_sumw2_np<<<Kk / 256, 256, 0, stream>>>(w, sw2);
        k_mfma_filter<<<Nn / 128, 512, 0, stream>>>(xbt, wbt, sw2, cmin);
        k_select<<<Nn / 256, 256, 0, stream>>>(cmin, cn, keys, cnt, lists);
        k_refine<<<dim3(64, 8), 256, 0, stream>>>(xT, wT, sw2, cn, cnt, lists, keys);
        k_quant2<<<Nn / 64, 256, 0, stream>>>(x, w, keys, outq, idxf, part);
        k_loss<<<1, 512, 0, stream>>>(part, loss);
    } else {
        // legacy round-2 path
        float* sw2 = (float*)(ws);
        int* idx = (int*)(ws + 32768);
        double* part = (double*)(ws + 163840);
        float* cn = (float*)(ws + 172032);
        float* wtg = (float*)(ws + 524288);
        const bool use_wtg = ws_size >= (size_t)524288 + (size_t)Kk * Dd * 4;
        if (use_wtg)
            k_transpose<<<dim3(Kk / 32, Dd / 32), dim3(32, 8), 0, stream>>>(w, wtg);
        k_sumx2_np<<<Nn / 256, 256, 0, stream>>>(x, cn);
        k_sumw2_np<<<Kk / 256, 256, 0, stream>>>(w, sw2);
        if (use_wtg)
            k_argmin<true><<<Nn / 128, 512, 0, stream>>>(x, w, wtg, sw2, cn, idx, idxf);
        else
            k_argmin<false><<<Nn / 128, 512, 0, stream>>>(x, w, wtg, sw2, cn, idx, idxf);
        k_quant<<<Nn / 64, 256, 0, stream>>>(x, w, idx, outq, part);
        k_loss<<<1, 512, 0, stream>>>(part, loss);
    }
}

// Round 5
// 889.403 us; speedup vs baseline: 1.9899x; 1.0773x over previous
//
#include <hip/hip_runtime.h>
#include <hip/hip_bf16.h>

#define Bn 32
#define Dd 256
#define Tt 1024
#define Nn (Bn * Tt)   // 32768
#define Kk 8192

typedef __attribute__((ext_vector_type(8))) short bf16x8;
typedef __attribute__((ext_vector_type(4))) float f32x4;

static __device__ __forceinline__ short f2bf(float v) {
    __hip_bfloat16 h = __float2bfloat16(v);
    return *reinterpret_cast<short*>(&h);
}

// ===================== ws layout (total == round-4's proven 75927808) ==========
#define OFF_XT    0ULL            // f32 [32768][256]  32 MB
#define OFF_XBT   33554432ULL     // bf16 [32768][256] 16 MB
#define OFF_WBT   50331648ULL     // bf16 [8192][256]   4 MB
#define OFF_CMA   54525952ULL     // f32 [64][32768]    8 MB (col-group 0 chunk-min)
#define OFF_CMB   62914560ULL     // f32 [64][32768]    8 MB (col-group 1 chunk-min)
#define OFF_LIST  71303168ULL     // u16 [64][32768]    4 MB
#define OFF_KEYS  75497472ULL     // u64 [32768]      256 KB
#define OFF_SW2   75759616ULL     // f32 [8192]
#define OFF_CN    75792384ULL     // f32 [32768]
#define OFF_CNT   75923456ULL     // u32 [64]
#define OFF_PART  75923712ULL     // f64 [512]
#define WS_NEED   75927808ULL

// ---- prep: x [b][d][t] -> xT f32 [n][d], xbt bf16 [n][d] ----
__global__ void k_xprep(const float* __restrict__ x, float* __restrict__ xT,
                        short* __restrict__ xbt) {
    __shared__ float tile[32][33];
    const int b = blockIdx.z, d0 = blockIdx.y * 32, t0 = blockIdx.x * 32;
    const int tx = threadIdx.x, ty = threadIdx.y;
#pragma unroll
    for (int r = 0; r < 32; r += 8)
        tile[ty + r][tx] = x[((size_t)(b * Dd + d0 + ty + r)) * Tt + t0 + tx];
    __syncthreads();
#pragma unroll
    for (int r = 0; r < 32; r += 8) {
        const size_t o = (size_t)(b * Tt + t0 + ty + r) * Dd + d0 + tx;
        const float v = tile[tx][ty + r];
        xT[o] = v;
        xbt[o] = f2bf(v);
    }
}

// ---- prep: w -> bf16 (elementwise; refine now uses w row-major directly) ----
__global__ void k_wbf(const float* __restrict__ w, short* __restrict__ wbt) {
    const int i = (blockIdx.x * 256 + threadIdx.x) * 4;
    const float4 v = *reinterpret_cast<const float4*>(&w[i]);
    short4 o;
    o.x = f2bf(v.x); o.y = f2bf(v.y); o.z = f2bf(v.z); o.w = f2bf(v.w);
    *reinterpret_cast<short4*>(&wbt[i]) = o;
}

// ---- numpy-pairwise-exact sum of squares (proven round 2) ----
__global__ void k_sumx2_np(const float* __restrict__ x, float* __restrict__ c) {
#pragma clang fp contract(off)
    const int n = blockIdx.x * 256 + threadIdx.x;
    const int b = n >> 10, t = n & 1023;
    const float* p = x + (size_t)b * (Dd * Tt) + t;
    float h[2];
#pragma unroll
    for (int half = 0; half < 2; ++half) {
        float r[8];
#pragma unroll
        for (int j = 0; j < 8; ++j) {
            const float v = p[(size_t)(half * 128 + j) * Tt];
            r[j] = v * v;
        }
        for (int i = 8; i < 128; i += 8) {
#pragma unroll
            for (int j = 0; j < 8; ++j) {
                const float v = p[(size_t)(half * 128 + i + j) * Tt];
                const float sq = v * v;
                r[j] = r[j] + sq;
            }
        }
        h[half] = ((r[0] + r[1]) + (r[2] + r[3])) + ((r[4] + r[5]) + (r[6] + r[7]));
    }
    c[n] = h[0] + h[1];
}

__global__ void k_sumw2_np(const float* __restrict__ w, float* __restrict__ sw) {
#pragma clang fp contract(off)
    const int k = blockIdx.x * 256 + threadIdx.x;
    const float* p = w + (size_t)k * Dd;
    float h[2];
#pragma unroll
    for (int half = 0; half < 2; ++half) {
        float r[8];
#pragma unroll
        for (int j = 0; j < 8; ++j) {
            const float v = p[half * 128 + j];
            r[j] = v * v;
        }
        for (int i = 8; i < 128; i += 8) {
#pragma unroll
            for (int j = 0; j < 8; ++j) {
                const float v = p[half * 128 + i + j];
                const float sq = v * v;
                r[j] = r[j] + sq;
            }
        }
        h[half] = ((r[0] + r[1]) + (r[2] + r[3])) + ((r[4] + r[5]) + (r[6] + r[7]));
    }
    sw[k] = h[0] + h[1];
}

// ---- stage 1: bf16 MFMA filter v2 ----
// 8 waves = 4 row-panels (32 rows) x 2 col-panels (64 codes). A in REGISTERS
// (loaded once, reused across 64 chunks); LDS holds only the W chunk.
// Col-panels write disjoint cma/cmb arrays -> no cross-wave combine (r3 lesson).
__global__ void __launch_bounds__(512, 2)
k_mfma_filter(const short* __restrict__ xbt, const short* __restrict__ wbt,
              const float* __restrict__ sw2,
              float* __restrict__ cma, float* __restrict__ cmb) {
    __shared__ __align__(16) short Ws[128 * 264];
    const int tid = threadIdx.x;
    const int n0 = blockIdx.x * 128;
    const int wid = tid >> 6, lane = tid & 63;
    const int rp = wid >> 1, cp = wid & 1;
    const int l15 = lane & 15, l4 = lane >> 4;

    // A fragments: rows 32rp+16rt+l15, all 8 k-slices (contiguous 8-bf16 at
    // d = 32ks + 8l4) — same fragment layout round 4 proved, sourced global.
    bf16x8 a[2][8];
#pragma unroll
    for (int rt = 0; rt < 2; ++rt)
#pragma unroll
        for (int ks = 0; ks < 8; ++ks)
            a[rt][ks] = *reinterpret_cast<const bf16x8*>(
                &xbt[(size_t)(n0 + 32 * rp + 16 * rt + l15) * Dd + 32 * ks + 8 * l4]);

    float* __restrict__ cm = cp ? cmb : cma;

    for (int c = 0; c < 64; ++c) {
        // stage W chunk: 128 codes x 256 d (16-B copies, coalesced)
#pragma unroll
        for (int m = 0; m < 8; ++m) {
            const int e = tid + 512 * m;      // 0..4095
            const int code = e >> 5, d8 = e & 31;
            *reinterpret_cast<bf16x8*>(&Ws[code * 264 + 8 * d8]) =
                *reinterpret_cast<const bf16x8*>(
                    &wbt[(size_t)(128 * c + code) * Dd + 8 * d8]);
        }
        __syncthreads();

        f32x4 acc[2][4];
#pragma unroll
        for (int rt = 0; rt < 2; ++rt)
#pragma unroll
            for (int ct = 0; ct < 4; ++ct) acc[rt][ct] = (f32x4)0.0f;

#pragma unroll
        for (int ks = 0; ks < 8; ++ks) {
            bf16x8 b[4];
#pragma unroll
            for (int ct = 0; ct < 4; ++ct)
                b[ct] = *reinterpret_cast<const bf16x8*>(
                    &Ws[(64 * cp + 16 * ct + l15) * 264 + 32 * ks + 8 * l4]);
#pragma unroll
            for (int rt = 0; rt < 2; ++rt)
#pragma unroll
                for (int ct = 0; ct < 4; ++ct)
                    acc[rt][ct] = __builtin_amdgcn_mfma_f32_16x16x32_bf16(
                        a[rt][ks], b[ct], acc[rt][ct], 0, 0, 0);
        }
        __syncthreads();   // Ws reads done; next iteration may restage

        // epilogue: u = sw - 2*dot; per-row min over this col-panel's 64 codes
        float swc[4];
#pragma unroll
        for (int ct = 0; ct < 4; ++ct)
            swc[ct] = sw2[128 * c + 64 * cp + 16 * ct + l15];
#pragma unroll
        for (int rt = 0; rt < 2; ++rt) {
#pragma unroll
            for (int r = 0; r < 4; ++r) {
                float mm = fmaf(-2.0f, acc[rt][0][r], swc[0]);
#pragma unroll
                for (int ct = 1; ct < 4; ++ct)
                    mm = fminf(mm, fmaf(-2.0f, acc[rt][ct][r], swc[ct]));
#pragma unroll
                for (int d = 1; d < 16; d <<= 1)
                    mm = fminf(mm, __shfl_xor(mm, d));
                if (l15 == 0) {
                    const int row = n0 + 32 * rp + 16 * rt + 4 * l4 + r;
                    cm[(size_t)c * Nn + row] = mm;   // [c][n]: coalesced-ish
                }
            }
        }
    }
}

// ---- select: margin filter -> per-chunk row lists; init keys ----
__global__ void k_select(const float* __restrict__ cma, const float* __restrict__ cmb,
                         const float* __restrict__ cn,
                         unsigned long long* __restrict__ keys,
                         unsigned int* __restrict__ cnt,
                         unsigned short* __restrict__ lists) {
    const int n = blockIdx.x * 256 + threadIdx.x;
    float gmin = 3.402823466e+38f;
    for (int c = 0; c < 64; ++c)
        gmin = fminf(gmin, fminf(cma[(size_t)c * Nn + n], cmb[(size_t)c * Nn + n]));
    keys[n] = 0xFFFFFFFFFFFFFFFFULL;
    const float margin = 7.1e-5f + 2.6e-5f * sqrtf(cn[n]);
    const float thr = gmin + margin;
    for (int c = 0; c < 64; ++c) {
        if (fminf(cma[(size_t)c * Nn + n], cmb[(size_t)c * Nn + n]) <= thr) {
            const unsigned int pos = atomicAdd(&cnt[c], 1u);
            lists[(size_t)c * Nn + pos] = (unsigned short)n;
        }
    }
}

// ---- refine v2: exact f32 recompute, 4x4 thread tile, no sm buffer ----
// 512 thr = 32 code-lanes x 16 row-groups; thread = 4 rows x 4 codes.
// w read as contiguous float4 from original [k][d] layout (L1-resident).
// Chain per (row,code): ascending-d fmaf — bit-identical to round-2 kernel.
__global__ void __launch_bounds__(512, 4)
k_refine(const float* __restrict__ xT, const float* __restrict__ w,
         const float* __restrict__ sw2, const float* __restrict__ cn,
         const unsigned int* __restrict__ cnt, const unsigned short* __restrict__ lists,
         unsigned long long* __restrict__ keys) {
    __shared__ __align__(16) float xs[64 * 260];
    __shared__ float cns[64];
    __shared__ unsigned short rid_s[64];
    const int c = blockIdx.x, gb = blockIdx.y;
    const int tid = threadIdx.x;
    const int cntc = (int)cnt[c];
    const int kl = tid & 31, rg = tid >> 5;   // rg 0..15
    float swk[4];
#pragma unroll
    for (int cc = 0; cc < 4; ++cc) swk[cc] = sw2[128 * c + kl + 32 * cc];

    for (int start = gb * 64; start < cntc; start += 8 * 64) {
        // stage 64 candidate rows (one full 1-KB row per wave-load)
#pragma unroll
        for (int m = 0; m < 8; ++m) {
            const int e = tid + 512 * m;      // 0..4095
            const int j = e >> 6, d4 = e & 63;
            const int li = min(start + j, cntc - 1);
            const int row = lists[(size_t)c * Nn + li];
            *reinterpret_cast<float4*>(&xs[j * 260 + 4 * d4]) =
                *reinterpret_cast<const float4*>(&xT[(size_t)row * Dd + 4 * d4]);
        }
        if (tid < 64) {
            const int li = min(start + tid, cntc - 1);
            const unsigned short row = lists[(size_t)c * Nn + li];
            rid_s[tid] = row;
            cns[tid] = cn[row];
        }
        __syncthreads();

        float acc[4][4];
#pragma unroll
        for (int rr = 0; rr < 4; ++rr)
#pragma unroll
            for (int cc = 0; cc < 4; ++cc) acc[rr][cc] = 0.0f;

        for (int d4 = 0; d4 < 64; ++d4) {
            float4 wv[4];
#pragma unroll
            for (int cc = 0; cc < 4; ++cc)
                wv[cc] = *reinterpret_cast<const float4*>(
                    &w[(size_t)(128 * c + kl + 32 * cc) * Dd + 4 * d4]);
#pragma unroll
            for (int rr = 0; rr < 4; ++rr) {
                const float4 xv = *reinterpret_cast<const float4*>(
                    &xs[(4 * rg + rr) * 260 + 4 * d4]);
#pragma unroll
                for (int cc = 0; cc < 4; ++cc) {
                    acc[rr][cc] = fmaf(xv.x, wv[cc].x, acc[rr][cc]);
                    acc[rr][cc] = fmaf(xv.y, wv[cc].y, acc[rr][cc]);
                    acc[rr][cc] = fmaf(xv.z, wv[cc].z, acc[rr][cc]);
                    acc[rr][cc] = fmaf(xv.w, wv[cc].w, acc[rr][cc]);
                }
            }
        }

        // per-row argmin: fold 4 codes in-thread, then 32-lane shuffle reduce
#pragma unroll
        for (int rr = 0; rr < 4; ++rr) {
            const int rl = 4 * rg + rr;
            const float cr = cns[rl];
            float bv = 3.402823466e+38f;
            int bk = 0x7FFFFFFF;
#pragma unroll
            for (int cc = 0; cc < 4; ++cc) {
                const float t1 = cr + swk[cc];               // fl32(cn + sw)
                const float s = fmaf(-2.0f, acc[rr][cc], t1); // fl32(t1 - 2*dot)
                const int k = 128 * c + kl + 32 * cc;
                if (s < bv || (s == bv && k < bk)) { bv = s; bk = k; }
            }
#pragma unroll
            for (int d = 1; d < 32; d <<= 1) {
                const float ov = __shfl_xor(bv, d);
                const int ok = __shfl_xor(bk, d);
                if (ov < bv || (ov == bv && ok < bk)) { bv = ov; bk = ok; }
            }
            if (kl == 0) {
                const unsigned long long key =
                    ((unsigned long long)__float_as_uint(bv) << 32) |
                    (unsigned long long)(unsigned int)bk;
                atomicMin(&keys[rid_s[rl]], key);
            }
        }
        __syncthreads();
    }
}

// ---- gather + STE + partial loss (proven, key-indexed) ----
__global__ void k_quant2(const float* __restrict__ x, const float* __restrict__ w,
                         const unsigned long long* __restrict__ keys,
                         float* __restrict__ outq, float* __restrict__ idxf,
                         double* __restrict__ part) {
#pragma clang fp contract(off)
    __shared__ double red[256];
    const int tid = threadIdx.x;
    const int n0 = blockIdx.x * 64;
    const int b = n0 >> 10, t0 = n0 & 1023;
    const int tl = tid & 63;
    const int d0 = tid >> 6;
    const int n = n0 + tl;
    const int code = (int)(unsigned int)(keys[n] & 0xFFFFFFFFULL);
    if (tid < 64) idxf[n0 + tid] = (float)(int)(unsigned int)(keys[n0 + tid] & 0xFFFFFFFFULL);
    const float* wr = w + (size_t)code * Dd;
    const size_t base = (size_t)b * (Dd * Tt) + t0 + tl;
    double s = 0.0;
    for (int d = d0; d < Dd; d += 4) {
        const float xv = x[base + (size_t)d * Tt];
        const float qv = wr[d];
        const float d1 = qv - xv;
        const float qs = xv + d1;
        const float d2 = qs - xv;
        s += (double)d2 * (double)d2;
        outq[base + (size_t)d * Tt] = qs;
    }
    red[tid] = s;
    __syncthreads();
    for (int st = 128; st > 0; st >>= 1) {
        if (tid < st) red[tid] += red[tid + st];
        __syncthreads();
    }
    if (tid == 0) part[blockIdx.x] = red[0];
}

__global__ void k_loss(const double* __restrict__ part, float* __restrict__ loss) {
    __shared__ double red[512];
    const int tid = threadIdx.x;
    red[tid] = part[tid];
    __syncthreads();
    for (int st = 256; st > 0; st >>= 1) {
        if (tid < st) red[tid] += red[tid + st];
        __syncthreads();
    }
    if (tid == 0)
        loss[0] = (float)(1.25 * red[0] / (double)((size_t)Bn * Dd * Tt));
}

// ===================== LEGACY (round-2 proven) FALLBACK =====================
__global__ void k_transpose(const float* __restrict__ w, float* __restrict__ wtg) {
    __shared__ float tile[32][33];
    const int k0 = blockIdx.x * 32;
    const int d0 = blockIdx.y * 32;
    const int tx = threadIdx.x, ty = threadIdx.y;
#pragma unroll
    for (int r = 0; r < 32; r += 8)
        tile[r + ty][tx] = w[(size_t)(k0 + r + ty) * Dd + d0 + tx];
    __syncthreads();
#pragma unroll
    for (int r = 0; r < 32; r += 8)
        wtg[(size_t)(d0 + r + ty) * Kk + k0 + tx] = tile[tx][r + ty];
}

template <bool WTG>
__global__ void __launch_bounds__(512, 2)
k_argmin(const float* __restrict__ x, const float* __restrict__ w,
         const float* __restrict__ wtg, const float* __restrict__ sw2,
         const float* __restrict__ cn,
         int* __restrict__ idx_out, float* __restrict__ idx_f) {
    __shared__ __align__(16) float At[32][132];
    __shared__ __align__(16) float Wt[32][268];
    const int tid = threadIdx.x;
    const int n0 = blockIdx.x * 128;
    const int b = n0 >> 10;
    const int t0 = n0 & 1023;
    const int ty = tid >> 5;
    const int tx = tid & 31;
    const int r0 = ty * 4;
    const int c0 = tx * 4;
    const float* xb = x + (size_t)b * (Dd * Tt) + t0;

    float c8[8];
#pragma unroll
    for (int i = 0; i < 8; ++i) {
        const int row = (i < 4) ? (r0 + i) : (64 + r0 + (i - 4));
        c8[i] = cn[n0 + row];
    }
    float best[8];
    int bidx[8];
#pragma unroll
    for (int i = 0; i < 8; ++i) { best[i] = 3.402823466e+38f; bidx[i] = 0; }

    for (int kc = 0; kc < Kk; kc += 256) {
        float acc[8][8];
#pragma unroll
        for (int i = 0; i < 8; ++i)
#pragma unroll
            for (int j = 0; j < 8; ++j) acc[i][j] = 0.0f;
        for (int ds = 0; ds < Dd; ds += 32) {
#pragma unroll
            for (int u = 0; u < 2; ++u) {
                int cc = tid + 512 * u;
                int dd = cc >> 5, i4 = cc & 31;
                float4 v = *reinterpret_cast<const float4*>(
                    &xb[(size_t)(ds + dd) * Tt + i4 * 4]);
                *reinterpret_cast<float4*>(&At[dd][i4 * 4]) = v;
            }
            if (WTG) {
#pragma unroll
                for (int u = 0; u < 4; ++u) {
                    int cc = tid + 512 * u;
                    int dd = cc >> 6, j4 = cc & 63;
                    float4 v = *reinterpret_cast<const float4*>(
                        &wtg[(size_t)(ds + dd) * Kk + kc + j4 * 4]);
                    *reinterpret_cast<float4*>(&Wt[dd][j4 * 4]) = v;
                }
            } else {
#pragma unroll
                for (int u = 0; u < 4; ++u) {
                    int cc = tid + 512 * u;
                    int j = cc >> 3, m = cc & 7;
                    float4 v = *reinterpret_cast<const float4*>(
                        &w[(size_t)(kc + j) * Dd + ds + m * 4]);
                    Wt[m * 4 + 0][j] = v.x;
                    Wt[m * 4 + 1][j] = v.y;
                    Wt[m * 4 + 2][j] = v.z;
                    Wt[m * 4 + 3][j] = v.w;
                }
            }
            __syncthreads();
#pragma unroll 8
            for (int dd = 0; dd < 32; ++dd) {
                float4 a0 = *reinterpret_cast<const float4*>(&At[dd][r0]);
                float4 a1 = *reinterpret_cast<const float4*>(&At[dd][64 + r0]);
                float4 b0 = *reinterpret_cast<const float4*>(&Wt[dd][c0]);
                float4 b1 = *reinterpret_cast<const float4*>(&Wt[dd][128 + c0]);
                float av[8] = {a0.x, a0.y, a0.z, a0.w, a1.x, a1.y, a1.z, a1.w};
                float bv[8] = {b0.x, b0.y, b0.z, b0.w, b1.x, b1.y, b1.z, b1.w};
#pragma unroll
                for (int i = 0; i < 8; ++i)
#pragma unroll
                    for (int j = 0; j < 8; ++j)
                        acc[i][j] = fmaf(av[i], bv[j], acc[i][j]);
            }
            __syncthreads();
        }
#pragma unroll
        for (int j = 0; j < 8; ++j) {
            const int col = (j < 4) ? (c0 + j) : (128 + c0 + (j - 4));
            const int k = kc + col;
            const float sw = sw2[k];
#pragma unroll
            for (int i = 0; i < 8; ++i) {
                const float t1 = c8[i] + sw;
                const float s = fmaf(-2.0f, acc[i][j], t1);
                if (s < best[i] || (s == best[i] && k < bidx[i])) {
                    best[i] = s; bidx[i] = k;
                }
            }
        }
    }
#pragma unroll
    for (int i = 0; i < 8; ++i) {
        float v = best[i];
        int id = bidx[i];
#pragma unroll
        for (int m = 1; m < 32; m <<= 1) {
            const float ov = __shfl_xor(v, m);
            const int oi = __shfl_xor(id, m);
            if (ov < v || (ov == v && oi < id)) { v = ov; id = oi; }
        }
        if (tx == 0) {
            const int row = (i < 4) ? (r0 + i) : (64 + r0 + (i - 4));
            const int n = n0 + row;
            idx_out[n] = id;
            idx_f[n] = (float)id;
        }
    }
}

__global__ void k_quant(const float* __restrict__ x, const float* __restrict__ w,
                        const int* __restrict__ idx, float* __restrict__ outq,
                        double* __restrict__ part) {
#pragma clang fp contract(off)
    __shared__ double red[256];
    const int tid = threadIdx.x;
    const int n0 = blockIdx.x * 64;
    const int b = n0 >> 10, t0 = n0 & 1023;
    const int tl = tid & 63;
    const int d0 = tid >> 6;
    const int n = n0 + tl;
    const int code = idx[n];
    const float* wr = w + (size_t)code * Dd;
    const size_t base = (size_t)b * (Dd * Tt) + t0 + tl;
    double s = 0.0;
    for (int d = d0; d < Dd; d += 4) {
        const float xv = x[base + (size_t)d * Tt];
        const float qv = wr[d];
        const float d1 = qv - xv;
        const float qs = xv + d1;
        const float d2 = qs - xv;
        s += (double)d2 * (double)d2;
        outq[base + (size_t)d * Tt] = qs;
    }
    red[tid] = s;
    __syncthreads();
    for (int st = 128; st > 0; st >>= 1) {
        if (tid < st) red[tid] += red[tid + st];
        __syncthreads();
    }
    if (tid == 0) part[blockIdx.x] = red[0];
}

// ===================== host =====================
extern "C" void kernel_launch(void* const* d_in, const int* in_sizes, int n_in,
                              void* d_out, int out_size, void* d_ws, size_t ws_size,
                              hipStream_t stream) {
    const float* x = (const float*)d_in[0];
    const float* w = (const float*)d_in[1];
    float* out = (float*)d_out;
    float* loss = out;
    float* outq = out + 1;
    float* idxf = out + 1 + (size_t)Bn * Dd * Tt;
    char* ws = (char*)d_ws;

    if (ws_size >= WS_NEED) {
        float* xT = (float*)(ws + OFF_XT);
        short* xbt = (short*)(ws + OFF_XBT);
        short* wbt = (short*)(ws + OFF_WBT);
        float* cma = (float*)(ws + OFF_CMA);
        float* cmb = (float*)(ws + OFF_CMB);
        unsigned short* lists = (unsigned short*)(ws + OFF_LIST);
        unsigned long long* keys = (unsigned long long*)(ws + OFF_KEYS);
        float* sw2 = (float*)(ws + OFF_SW2);
        float* cn = (float*)(ws + OFF_CN);
        unsigned int* cnt = (unsigned int*)(ws + OFF_CNT);
        double* part = (double*)(ws + OFF_PART);

        hipMemsetAsync(cnt, 0, 64 * sizeof(unsigned int), stream);
        k_xprep<<<dim3(32, 8, 32), dim3(32, 8), 0, stream>>>(x, xT, xbt);
        k_wbf<<<(Kk * Dd) / 1024, 256, 0, stream>>>(w, wbt);
        k_sumx2_np<<<Nn / 256, 256, 0, stream>>>(x, cn);
        k_sumw2_np<<<Kk / 256, 256, 0, stream>>>(w, sw2);
        k_mfma_filter<<<Nn / 128, 512, 0, stream>>>(xbt, wbt, sw2, cma, cmb);
        k_select<<<Nn / 256, 256, 0, stream>>>(cma, cmb, cn, keys, cnt, lists);
        k_refine<<<dim3(64, 8), 512, 0, stream>>>(xT, w, sw2, cn, cnt, lists, keys);
        k_quant2<<<Nn / 64, 256, 0, stream>>>(x, w, keys, outq, idxf, part);
        k_loss<<<1, 512, 0, stream>>>(part, loss);
    } else {
        // legacy round-2 path
        float* sw2 = (float*)(ws);
        int* idx = (int*)(ws + 32768);
        double* part = (double*)(ws + 163840);
        float* cn = (float*)(ws + 172032);
        float* wtg = (float*)(ws + 524288);
        const bool use_wtg = ws_size >= (size_t)524288 + (size_t)Kk * Dd * 4;
        if (use_wtg)
            k_transpose<<<dim3(Kk / 32, Dd / 32), dim3(32, 8), 0, stream>>>(w, wtg);
        k_sumx2_np<<<Nn / 256, 256, 0, stream>>>(x, cn);
        k_sumw2_np<<<Kk / 256, 256, 0, stream>>>(w, sw2);
        if (use_wtg)
            k_argmin<true><<<Nn / 128, 512, 0, stream>>>(x, w, wtg, sw2, cn, idx, idxf);
        else
            k_argmin<false><<<Nn / 128, 512, 0, stream>>>(x, w, wtg, sw2, cn, idx, idxf);
        k_quant<<<Nn / 64, 256, 0, stream>>>(x, w, idx, outq, part);
        k_loss<<<1, 512, 0, stream>>>(part, loss);
    }
}

// Round 6
// 763.363 us; speedup vs baseline: 2.3184x; 1.1651x over previous
//
#include <hip/hip_runtime.h>
#include <hip/hip_bf16.h>

#define Bn 32
#define Dd 256
#define Tt 1024
#define Nn (Bn * Tt)   // 32768
#define Kk 8192

typedef __attribute__((ext_vector_type(8))) short bf16x8;
typedef __attribute__((ext_vector_type(4))) float f32x4;

static __device__ __forceinline__ short f2bf(float v) {
    __hip_bfloat16 h = __float2bfloat16(v);
    return *reinterpret_cast<short*>(&h);
}

// ===================== ws layout (total == proven 75927808) ====================
#define OFF_XT    0ULL            // f32 [32768][256]  32 MB
#define OFF_XBT   33554432ULL     // bf16 [32768][256] 16 MB
#define OFF_WBT   50331648ULL     // bf16 [8192][256]   4 MB
#define OFF_CM    54525952ULL     // f32 [32768][128]  16 MB  (chunk-min, col=2c+cp)
#define OFF_LIST  71303168ULL     // u16 [64][32768]    4 MB
#define OFF_KEYS  75497472ULL     // u64 [32768]      256 KB
#define OFF_SW2   75759616ULL     // f32 [8192]
#define OFF_CN    75792384ULL     // f32 [32768]
#define OFF_CNT   75923456ULL     // u32 [64]
#define OFF_PART  75923712ULL     // f64 [512]
#define WS_NEED   75927808ULL

// ---- prep: x [b][d][t] -> xT f32 [n][d], xbt bf16 [n][d] ----
__global__ void k_xprep(const float* __restrict__ x, float* __restrict__ xT,
                        short* __restrict__ xbt) {
    __shared__ float tile[32][33];
    const int b = blockIdx.z, d0 = blockIdx.y * 32, t0 = blockIdx.x * 32;
    const int tx = threadIdx.x, ty = threadIdx.y;
#pragma unroll
    for (int r = 0; r < 32; r += 8)
        tile[ty + r][tx] = x[((size_t)(b * Dd + d0 + ty + r)) * Tt + t0 + tx];
    __syncthreads();
#pragma unroll
    for (int r = 0; r < 32; r += 8) {
        const size_t o = (size_t)(b * Tt + t0 + ty + r) * Dd + d0 + tx;
        const float v = tile[tx][ty + r];
        xT[o] = v;
        xbt[o] = f2bf(v);
    }
}

// ---- prep: w -> bf16 elementwise ----
__global__ void k_wbf(const float* __restrict__ w, short* __restrict__ wbt) {
    const int i = (blockIdx.x * 256 + threadIdx.x) * 4;
    const float4 v = *reinterpret_cast<const float4*>(&w[i]);
    short4 o;
    o.x = f2bf(v.x); o.y = f2bf(v.y); o.z = f2bf(v.z); o.w = f2bf(v.w);
    *reinterpret_cast<short4*>(&wbt[i]) = o;
}

// ---- numpy-pairwise-exact sum of squares (proven round 2) ----
__global__ void k_sumx2_np(const float* __restrict__ x, float* __restrict__ c) {
#pragma clang fp contract(off)
    const int n = blockIdx.x * 256 + threadIdx.x;
    const int b = n >> 10, t = n & 1023;
    const float* p = x + (size_t)b * (Dd * Tt) + t;
    float h[2];
#pragma unroll
    for (int half = 0; half < 2; ++half) {
        float r[8];
#pragma unroll
        for (int j = 0; j < 8; ++j) {
            const float v = p[(size_t)(half * 128 + j) * Tt];
            r[j] = v * v;
        }
        for (int i = 8; i < 128; i += 8) {
#pragma unroll
            for (int j = 0; j < 8; ++j) {
                const float v = p[(size_t)(half * 128 + i + j) * Tt];
                const float sq = v * v;
                r[j] = r[j] + sq;
            }
        }
        h[half] = ((r[0] + r[1]) + (r[2] + r[3])) + ((r[4] + r[5]) + (r[6] + r[7]));
    }
    c[n] = h[0] + h[1];
}

__global__ void k_sumw2_np(const float* __restrict__ w, float* __restrict__ sw) {
#pragma clang fp contract(off)
    const int k = blockIdx.x * 256 + threadIdx.x;
    const float* p = w + (size_t)k * Dd;
    float h[2];
#pragma unroll
    for (int half = 0; half < 2; ++half) {
        float r[8];
#pragma unroll
        for (int j = 0; j < 8; ++j) {
            const float v = p[half * 128 + j];
            r[j] = v * v;
        }
        for (int i = 8; i < 128; i += 8) {
#pragma unroll
            for (int j = 0; j < 8; ++j) {
                const float v = p[half * 128 + i + j];
                const float sq = v * v;
                r[j] = r[j] + sq;
            }
        }
        h[half] = ((r[0] + r[1]) + (r[2] + r[3])) + ((r[4] + r[5]) + (r[6] + r[7]));
    }
    sw[k] = h[0] + h[1];
}

// ---- stage 1: bf16 MFMA filter (round-5 proven; only the cm write changed) ----
__global__ void __launch_bounds__(512, 2)
k_mfma_filter(const short* __restrict__ xbt, const short* __restrict__ wbt,
              const float* __restrict__ sw2, float* __restrict__ cm) {
    __shared__ __align__(16) short Ws[128 * 264];
    const int tid = threadIdx.x;
    const int n0 = blockIdx.x * 128;
    const int wid = tid >> 6, lane = tid & 63;
    const int rp = wid >> 1, cp = wid & 1;
    const int l15 = lane & 15, l4 = lane >> 4;

    bf16x8 a[2][8];
#pragma unroll
    for (int rt = 0; rt < 2; ++rt)
#pragma unroll
        for (int ks = 0; ks < 8; ++ks)
            a[rt][ks] = *reinterpret_cast<const bf16x8*>(
                &xbt[(size_t)(n0 + 32 * rp + 16 * rt + l15) * Dd + 32 * ks + 8 * l4]);

    for (int c = 0; c < 64; ++c) {
#pragma unroll
        for (int m = 0; m < 8; ++m) {
            const int e = tid + 512 * m;      // 0..4095
            const int code = e >> 5, d8 = e & 31;
            *reinterpret_cast<bf16x8*>(&Ws[code * 264 + 8 * d8]) =
                *reinterpret_cast<const bf16x8*>(
                    &wbt[(size_t)(128 * c + code) * Dd + 8 * d8]);
        }
        __syncthreads();

        f32x4 acc[2][4];
#pragma unroll
        for (int rt = 0; rt < 2; ++rt)
#pragma unroll
            for (int ct = 0; ct < 4; ++ct) acc[rt][ct] = (f32x4)0.0f;

#pragma unroll
        for (int ks = 0; ks < 8; ++ks) {
            bf16x8 b[4];
#pragma unroll
            for (int ct = 0; ct < 4; ++ct)
                b[ct] = *reinterpret_cast<const bf16x8*>(
                    &Ws[(64 * cp + 16 * ct + l15) * 264 + 32 * ks + 8 * l4]);
#pragma unroll
            for (int rt = 0; rt < 2; ++rt)
#pragma unroll
                for (int ct = 0; ct < 4; ++ct)
                    acc[rt][ct] = __builtin_amdgcn_mfma_f32_16x16x32_bf16(
                        a[rt][ks], b[ct], acc[rt][ct], 0, 0, 0);
        }
        __syncthreads();

        float swc[4];
#pragma unroll
        for (int ct = 0; ct < 4; ++ct)
            swc[ct] = sw2[128 * c + 64 * cp + 16 * ct + l15];
#pragma unroll
        for (int rt = 0; rt < 2; ++rt) {
#pragma unroll
            for (int r = 0; r < 4; ++r) {
                float mm = fmaf(-2.0f, acc[rt][0][r], swc[0]);
#pragma unroll
                for (int ct = 1; ct < 4; ++ct)
                    mm = fminf(mm, fmaf(-2.0f, acc[rt][ct][r], swc[ct]));
#pragma unroll
                for (int d = 1; d < 16; d <<= 1)
                    mm = fminf(mm, __shfl_xor(mm, d));
                if (l15 == 0) {
                    const int row = n0 + 32 * rp + 16 * rt + 4 * l4 + r;
                    cm[(size_t)row * 128 + 2 * c + cp] = mm;   // [n][128], race-free
                }
            }
        }
    }
}

// ---- select v2: contiguous register-resident row scan ----
__global__ void __launch_bounds__(64)
k_select(const float* __restrict__ cm, const float* __restrict__ cn,
         unsigned long long* __restrict__ keys,
         unsigned int* __restrict__ cnt, unsigned short* __restrict__ lists) {
    const int n = blockIdx.x * 64 + threadIdx.x;
    float4 v[32];
#pragma unroll
    for (int i = 0; i < 32; ++i)
        v[i] = *reinterpret_cast<const float4*>(&cm[(size_t)n * 128 + 4 * i]);
    float gmin = 3.402823466e+38f;
#pragma unroll
    for (int i = 0; i < 32; ++i)
        gmin = fminf(gmin, fminf(fminf(v[i].x, v[i].y), fminf(v[i].z, v[i].w)));
    keys[n] = 0xFFFFFFFFFFFFFFFFULL;
    const float margin = 7.1e-5f + 2.6e-5f * sqrtf(cn[n]);
    const float thr = gmin + margin;
#pragma unroll
    for (int c = 0; c < 64; ++c) {
        const float4 q = v[c >> 1];
        const float m2 = (c & 1) ? fminf(q.z, q.w) : fminf(q.x, q.y);
        if (m2 <= thr) {
            const unsigned int pos = atomicAdd(&cnt[c], 1u);
            lists[(size_t)c * Nn + pos] = (unsigned short)n;
        }
    }
}

// ---- refine v3: both operands LDS-staged, coalesced; 8 rows x 4 codes/thread --
// 256 thr = 32 kl x 8 rg. Per slice: 64 candidate rows; w chunk staged in
// 4 d-steps of [128][64]. fmaf chain ascending-d == round-2 proven chain.
#define NGB 8
__global__ void __launch_bounds__(256, 1)
k_refine(const float* __restrict__ xT, const float* __restrict__ w,
         const float* __restrict__ sw2, const float* __restrict__ cn,
         const unsigned int* __restrict__ cnt, const unsigned short* __restrict__ lists,
         unsigned long long* __restrict__ keys) {
    __shared__ __align__(16) float xs[64 * 260];   // 66.5 KB
    __shared__ __align__(16) float ws[128 * 68];   // 34.8 KB
    __shared__ float cns[64];
    __shared__ unsigned short rid_s[64];
    const int c = blockIdx.x, gb = blockIdx.y;
    const int tid = threadIdx.x;
    const int cntc = (int)cnt[c];
    const int kl = tid & 31, rg = tid >> 5;   // rg 0..7
    float swk[4];
#pragma unroll
    for (int cc = 0; cc < 4; ++cc) swk[cc] = sw2[128 * c + kl + 32 * cc];

    for (int start = gb * 64; start < cntc; start += NGB * 64) {
        // stage 64 candidate rows (coalesced float4)
#pragma unroll
        for (int m = 0; m < 16; ++m) {
            const int e = tid + 256 * m;      // 0..4095
            const int j = e >> 6, d4 = e & 63;
            const int li = min(start + j, cntc - 1);
            const int row = lists[(size_t)c * Nn + li];
            *reinterpret_cast<float4*>(&xs[j * 260 + 4 * d4]) =
                *reinterpret_cast<const float4*>(&xT[(size_t)row * Dd + 4 * d4]);
        }
        if (tid < 64) {
            const int li = min(start + tid, cntc - 1);
            const unsigned short row = lists[(size_t)c * Nn + li];
            rid_s[tid] = row;
            cns[tid] = cn[row];
        }
        __syncthreads();

        float acc[8][4];
#pragma unroll
        for (int rr = 0; rr < 8; ++rr)
#pragma unroll
            for (int cc = 0; cc < 4; ++cc) acc[rr][cc] = 0.0f;

        for (int step = 0; step < 4; ++step) {
            // stage w d-slice: [128 codes][64 d] (coalesced float4)
#pragma unroll
            for (int m = 0; m < 8; ++m) {
                const int e = tid + 256 * m;  // 0..2047
                const int code = e >> 4, dseg = e & 15;
                *reinterpret_cast<float4*>(&ws[code * 68 + 4 * dseg]) =
                    *reinterpret_cast<const float4*>(
                        &w[(size_t)(128 * c + code) * Dd + step * 64 + 4 * dseg]);
            }
            __syncthreads();
#pragma unroll
            for (int dl = 0; dl < 16; ++dl) {
                float4 wv[4];
#pragma unroll
                for (int cc = 0; cc < 4; ++cc)
                    wv[cc] = *reinterpret_cast<const float4*>(
                        &ws[(kl + 32 * cc) * 68 + 4 * dl]);
#pragma unroll
                for (int rr = 0; rr < 8; ++rr) {
                    const float4 xv = *reinterpret_cast<const float4*>(
                        &xs[(8 * rg + rr) * 260 + step * 64 + 4 * dl]);
#pragma unroll
                    for (int cc = 0; cc < 4; ++cc) {
                        acc[rr][cc] = fmaf(xv.x, wv[cc].x, acc[rr][cc]);
                        acc[rr][cc] = fmaf(xv.y, wv[cc].y, acc[rr][cc]);
                        acc[rr][cc] = fmaf(xv.z, wv[cc].z, acc[rr][cc]);
                        acc[rr][cc] = fmaf(xv.w, wv[cc].w, acc[rr][cc]);
                    }
                }
            }
            __syncthreads();
        }

        // per-row argmin: fold 4 codes in-thread, 32-lane shuffle reduce
#pragma unroll
        for (int rr = 0; rr < 8; ++rr) {
            const int rl = 8 * rg + rr;
            const float cr = cns[rl];
            float bv = 3.402823466e+38f;
            int bk = 0x7FFFFFFF;
#pragma unroll
            for (int cc = 0; cc < 4; ++cc) {
                const float t1 = cr + swk[cc];                // fl32(cn + sw)
                const float s = fmaf(-2.0f, acc[rr][cc], t1); // fl32(t1 - 2*dot)
                const int k = 128 * c + kl + 32 * cc;
                if (s < bv || (s == bv && k < bk)) { bv = s; bk = k; }
            }
#pragma unroll
            for (int d = 1; d < 32; d <<= 1) {
                const float ov = __shfl_xor(bv, d);
                const int ok = __shfl_xor(bk, d);
                if (ov < bv || (ov == bv && ok < bk)) { bv = ov; bk = ok; }
            }
            if (kl == 0) {
                const unsigned long long key =
                    ((unsigned long long)__float_as_uint(bv) << 32) |
                    (unsigned long long)(unsigned int)bk;
                atomicMin(&keys[rid_s[rl]], key);
            }
        }
        __syncthreads();
    }
}

// ---- gather + STE + partial loss (proven, key-indexed) ----
__global__ void k_quant2(const float* __restrict__ x, const float* __restrict__ w,
                         const unsigned long long* __restrict__ keys,
                         float* __restrict__ outq, float* __restrict__ idxf,
                         double* __restrict__ part) {
#pragma clang fp contract(off)
    __shared__ double red[256];
    const int tid = threadIdx.x;
    const int n0 = blockIdx.x * 64;
    const int b = n0 >> 10, t0 = n0 & 1023;
    const int tl = tid & 63;
    const int d0 = tid >> 6;
    const int n = n0 + tl;
    const int code = (int)(unsigned int)(keys[n] & 0xFFFFFFFFULL);
    if (tid < 64) idxf[n0 + tid] = (float)(int)(unsigned int)(keys[n0 + tid] & 0xFFFFFFFFULL);
    const float* wr = w + (size_t)code * Dd;
    const size_t base = (size_t)b * (Dd * Tt) + t0 + tl;
    double s = 0.0;
    for (int d = d0; d < Dd; d += 4) {
        const float xv = x[base + (size_t)d * Tt];
        const float qv = wr[d];
        const float d1 = qv - xv;
        const float qs = xv + d1;
        const float d2 = qs - xv;
        s += (double)d2 * (double)d2;
        outq[base + (size_t)d * Tt] = qs;
    }
    red[tid] = s;
    __syncthreads();
    for (int st = 128; st > 0; st >>= 1) {
        if (tid < st) red[tid] += red[tid + st];
        __syncthreads();
    }
    if (tid == 0) part[blockIdx.x] = red[0];
}

__global__ void k_loss(const double* __restrict__ part, float* __restrict__ loss) {
    __shared__ double red[512];
    const int tid = threadIdx.x;
    red[tid] = part[tid];
    __syncthreads();
    for (int st = 256; st > 0; st >>= 1) {
        if (tid < st) red[tid] += red[tid + st];
        __syncthreads();
    }
    if (tid == 0)
        loss[0] = (float)(1.25 * red[0] / (double)((size_t)Bn * Dd * Tt));
}

// ===================== LEGACY (round-2 proven) FALLBACK =====================
__global__ void k_transpose(const float* __restrict__ w, float* __restrict__ wtg) {
    __shared__ float tile[32][33];
    const int k0 = blockIdx.x * 32;
    const int d0 = blockIdx.y * 32;
    const int tx = threadIdx.x, ty = threadIdx.y;
#pragma unroll
    for (int r = 0; r < 32; r += 8)
        tile[r + ty][tx] = w[(size_t)(k0 + r + ty) * Dd + d0 + tx];
    __syncthreads();
#pragma unroll
    for (int r = 0; r < 32; r += 8)
        wtg[(size_t)(d0 + r + ty) * Kk + k0 + tx] = tile[tx][r + ty];
}

template <bool WTG>
__global__ void __launch_bounds__(512, 2)
k_argmin(const float* __restrict__ x, const float* __restrict__ w,
         const float* __restrict__ wtg, const float* __restrict__ sw2,
         const float* __restrict__ cn,
         int* __restrict__ idx_out, float* __restrict__ idx_f) {
    __shared__ __align__(16) float At[32][132];
    __shared__ __align__(16) float Wt[32][268];
    const int tid = threadIdx.x;
    const int n0 = blockIdx.x * 128;
    const int b = n0 >> 10;
    const int t0 = n0 & 1023;
    const int ty = tid >> 5;
    const int tx = tid & 31;
    const int r0 = ty * 4;
    const int c0 = tx * 4;
    const float* xb = x + (size_t)b * (Dd * Tt) + t0;

    float c8[8];
#pragma unroll
    for (int i = 0; i < 8; ++i) {
        const int row = (i < 4) ? (r0 + i) : (64 + r0 + (i - 4));
        c8[i] = cn[n0 + row];
    }
    float best[8];
    int bidx[8];
#pragma unroll
    for (int i = 0; i < 8; ++i) { best[i] = 3.402823466e+38f; bidx[i] = 0; }

    for (int kc = 0; kc < Kk; kc += 256) {
        float acc[8][8];
#pragma unroll
        for (int i = 0; i < 8; ++i)
#pragma unroll
            for (int j = 0; j < 8; ++j) acc[i][j] = 0.0f;
        for (int ds = 0; ds < Dd; ds += 32) {
#pragma unroll
            for (int u = 0; u < 2; ++u) {
                int cc = tid + 512 * u;
                int dd = cc >> 5, i4 = cc & 31;
                float4 v = *reinterpret_cast<const float4*>(
                    &xb[(size_t)(ds + dd) * Tt + i4 * 4]);
                *reinterpret_cast<float4*>(&At[dd][i4 * 4]) = v;
            }
            if (WTG) {
#pragma unroll
                for (int u = 0; u < 4; ++u) {
                    int cc = tid + 512 * u;
                    int dd = cc >> 6, j4 = cc & 63;
                    float4 v = *reinterpret_cast<const float4*>(
                        &wtg[(size_t)(ds + dd) * Kk + kc + j4 * 4]);
                    *reinterpret_cast<float4*>(&Wt[dd][j4 * 4]) = v;
                }
            } else {
#pragma unroll
                for (int u = 0; u < 4; ++u) {
                    int cc = tid + 512 * u;
                    int j = cc >> 3, m = cc & 7;
                    float4 v = *reinterpret_cast<const float4*>(
                        &w[(size_t)(kc + j) * Dd + ds + m * 4]);
                    Wt[m * 4 + 0][j] = v.x;
                    Wt[m * 4 + 1][j] = v.y;
                    Wt[m * 4 + 2][j] = v.z;
                    Wt[m * 4 + 3][j] = v.w;
                }
            }
            __syncthreads();
#pragma unroll 8
            for (int dd = 0; dd < 32; ++dd) {
                float4 a0 = *reinterpret_cast<const float4*>(&At[dd][r0]);
                float4 a1 = *reinterpret_cast<const float4*>(&At[dd][64 + r0]);
                float4 b0 = *reinterpret_cast<const float4*>(&Wt[dd][c0]);
                float4 b1 = *reinterpret_cast<const float4*>(&Wt[dd][128 + c0]);
                float av[8] = {a0.x, a0.y, a0.z, a0.w, a1.x, a1.y, a1.z, a1.w};
                float bv[8] = {b0.x, b0.y, b0.z, b0.w, b1.x, b1.y, b1.z, b1.w};
#pragma unroll
                for (int i = 0; i < 8; ++i)
#pragma unroll
                    for (int j = 0; j < 8; ++j)
                        acc[i][j] = fmaf(av[i], bv[j], acc[i][j]);
            }
            __syncthreads();
        }
#pragma unroll
        for (int j = 0; j < 8; ++j) {
            const int col = (j < 4) ? (c0 + j) : (128 + c0 + (j - 4));
            const int k = kc + col;
            const float sw = sw2[k];
#pragma unroll
            for (int i = 0; i < 8; ++i) {
                const float t1 = c8[i] + sw;
                const float s = fmaf(-2.0f, acc[i][j], t1);
                if (s < best[i] || (s == best[i] && k < bidx[i])) {
                    best[i] = s; bidx[i] = k;
                }
            }
        }
    }
#pragma unroll
    for (int i = 0; i < 8; ++i) {
        float v = best[i];
        int id = bidx[i];
#pragma unroll
        for (int m = 1; m < 32; m <<= 1) {
            const float ov = __shfl_xor(v, m);
            const int oi = __shfl_xor(id, m);
            if (ov < v || (ov == v && oi < id)) { v = ov; id = oi; }
        }
        if (tx == 0) {
            const int row = (i < 4) ? (r0 + i) : (64 + r0 + (i - 4));
            const int n = n0 + row;
            idx_out[n] = id;
            idx_f[n] = (float)id;
        }
    }
}

__global__ void k_quant(const float* __restrict__ x, const float* __restrict__ w,
                        const int* __restrict__ idx, float* __restrict__ outq,
                        double* __restrict__ part) {
#pragma clang fp contract(off)
    __shared__ double red[256];
    const int tid = threadIdx.x;
    const int n0 = blockIdx.x * 64;
    const int b = n0 >> 10, t0 = n0 & 1023;
    const int tl = tid & 63;
    const int d0 = tid >> 6;
    const int n = n0 + tl;
    const int code = idx[n];
    const float* wr = w + (size_t)code * Dd;
    const size_t base = (size_t)b * (Dd * Tt) + t0 + tl;
    double s = 0.0;
    for (int d = d0; d < Dd; d += 4) {
        const float xv = x[base + (size_t)d * Tt];
        const float qv = wr[d];
        const float d1 = qv - xv;
        const float qs = xv + d1;
        const float d2 = qs - xv;
        s += (double)d2 * (double)d2;
        outq[base + (size_t)d * Tt] = qs;
    }
    red[tid] = s;
    __syncthreads();
    for (int st = 128; st > 0; st >>= 1) {
        if (tid < st) red[tid] += red[tid + st];
        __syncthreads();
    }
    if (tid == 0) part[blockIdx.x] = red[0];
}

// ===================== host =====================
extern "C" void kernel_launch(void* const* d_in, const int* in_sizes, int n_in,
                              void* d_out, int out_size, void* d_ws, size_t ws_size,
                              hipStream_t stream) {
    const float* x = (const float*)d_in[0];
    const float* w = (const float*)d_in[1];
    float* out = (float*)d_out;
    float* loss = out;
    float* outq = out + 1;
    float* idxf = out + 1 + (size_t)Bn * Dd * Tt;
    char* ws = (char*)d_ws;

    if (ws_size >= WS_NEED) {
        float* xT = (float*)(ws + OFF_XT);
        short* xbt = (short*)(ws + OFF_XBT);
        short* wbt = (short*)(ws + OFF_WBT);
        float* cm = (float*)(ws + OFF_CM);
        unsigned short* lists = (unsigned short*)(ws + OFF_LIST);
        unsigned long long* keys = (unsigned long long*)(ws + OFF_KEYS);
        float* sw2 = (float*)(ws + OFF_SW2);
        float* cn = (float*)(ws + OFF_CN);
        unsigned int* cnt = (unsigned int*)(ws + OFF_CNT);
        double* part = (double*)(ws + OFF_PART);

        hipMemsetAsync(cnt, 0, 64 * sizeof(unsigned int), stream);
        k_xprep<<<dim3(32, 8, 32), dim3(32, 8), 0, stream>>>(x, xT, xbt);
        k_wbf<<<(Kk * Dd) / 1024, 256, 0, stream>>>(w, wbt);
        k_sumx2_np<<<Nn / 256, 256, 0, stream>>>(x, cn);
        k_sumw2_np<<<Kk / 256, 256, 0, stream>>>(w, sw2);
        k_mfma_filter<<<Nn / 128, 512, 0, stream>>>(xbt, wbt, sw2, cm);
        k_select<<<Nn / 64, 64, 0, stream>>>(cm, cn, keys, cnt, lists);
        k_refine<<<dim3(64, NGB), 256, 0, stream>>>(xT, w, sw2, cn, cnt, lists, keys);
        k_quant2<<<Nn / 64, 256, 0, stream>>>(x, w, keys, outq, idxf, part);
        k_loss<<<1, 512, 0, stream>>>(part, loss);
    } else {
        // legacy round-2 path
        float* sw2 = (float*)(ws);
        int* idx = (int*)(ws + 32768);
        double* part = (double*)(ws + 163840);
        float* cn = (float*)(ws + 172032);
        float* wtg = (float*)(ws + 524288);
        const bool use_wtg = ws_size >= (size_t)524288 + (size_t)Kk * Dd * 4;
        if (use_wtg)
            k_transpose<<<dim3(Kk / 32, Dd / 32), dim3(32, 8), 0, stream>>>(w, wtg);
        k_sumx2_np<<<Nn / 256, 256, 0, stream>>>(x, cn);
        k_sumw2_np<<<Kk / 256, 256, 0, stream>>>(w, sw2);
        if (use_wtg)
            k_argmin<true><<<Nn / 128, 512, 0, stream>>>(x, w, wtg, sw2, cn, idx, idxf);
        else
            k_argmin<false><<<Nn / 128, 512, 0, stream>>>(x, w, wtg, sw2, cn, idx, idxf);
        k_quant<<<Nn / 64, 256, 0, stream>>>(x, w, idx, outq, part);
        k_loss<<<1, 512, 0, stream>>>(part, loss);
    }
}

// Round 7
// 487.637 us; speedup vs baseline: 3.6293x; 1.5654x over previous
//
#include <hip/hip_runtime.h>
#include <hip/hip_bf16.h>

#define Bn 32
#define Dd 256
#define Tt 1024
#define Nn (Bn * Tt)   // 32768
#define Kk 8192

typedef __attribute__((ext_vector_type(8))) short bf16x8;
typedef __attribute__((ext_vector_type(4))) float f32x4;

static __device__ __forceinline__ short f2bf(float v) {
    __hip_bfloat16 h = __float2bfloat16(v);
    return *reinterpret_cast<short*>(&h);
}

// ===================== ws layout (total == proven 75927808) ====================
#define OFF_XT    0ULL            // f32 [32768][256]  32 MB
#define OFF_XBT   33554432ULL     // bf16 [32768][256] 16 MB (dead after filter -> mask reuses)
#define OFF_WBT   50331648ULL     // bf16 [8192][256]   4 MB
#define OFF_CM    54525952ULL     // f32 [32768][128]  16 MB  (chunk-min, col=2c+cp)
#define OFF_LIST  71303168ULL     // u16 [64][32768]    4 MB
#define OFF_KEYS  75497472ULL     // u64 [32768]      256 KB
#define OFF_SW2   75759616ULL     // f32 [8192]
#define OFF_CN    75792384ULL     // f32 [32768]
#define OFF_CNT   75923456ULL     // u32 [64]
#define OFF_PART  75923712ULL     // f64 [512]
#define WS_NEED   75927808ULL
#define OFF_MASK  OFF_XBT         // u64 [32768] 256 KB, aliases dead xbt

// ---- prep: x [b][d][t] -> xT f32 [n][d], xbt bf16 [n][d] ----
__global__ void k_xprep(const float* __restrict__ x, float* __restrict__ xT,
                        short* __restrict__ xbt) {
    __shared__ float tile[32][33];
    const int b = blockIdx.z, d0 = blockIdx.y * 32, t0 = blockIdx.x * 32;
    const int tx = threadIdx.x, ty = threadIdx.y;
#pragma unroll
    for (int r = 0; r < 32; r += 8)
        tile[ty + r][tx] = x[((size_t)(b * Dd + d0 + ty + r)) * Tt + t0 + tx];
    __syncthreads();
#pragma unroll
    for (int r = 0; r < 32; r += 8) {
        const size_t o = (size_t)(b * Tt + t0 + ty + r) * Dd + d0 + tx;
        const float v = tile[tx][ty + r];
        xT[o] = v;
        xbt[o] = f2bf(v);
    }
}

// ---- prep: w -> bf16 elementwise ----
__global__ void k_wbf(const float* __restrict__ w, short* __restrict__ wbt) {
    const int i = (blockIdx.x * 256 + threadIdx.x) * 4;
    const float4 v = *reinterpret_cast<const float4*>(&w[i]);
    short4 o;
    o.x = f2bf(v.x); o.y = f2bf(v.y); o.z = f2bf(v.z); o.w = f2bf(v.w);
    *reinterpret_cast<short4*>(&wbt[i]) = o;
}

// ---- numpy-pairwise-exact sum of squares (proven round 2) ----
__global__ void k_sumx2_np(const float* __restrict__ x, float* __restrict__ c) {
#pragma clang fp contract(off)
    const int n = blockIdx.x * 256 + threadIdx.x;
    const int b = n >> 10, t = n & 1023;
    const float* p = x + (size_t)b * (Dd * Tt) + t;
    float h[2];
#pragma unroll
    for (int half = 0; half < 2; ++half) {
        float r[8];
#pragma unroll
        for (int j = 0; j < 8; ++j) {
            const float v = p[(size_t)(half * 128 + j) * Tt];
            r[j] = v * v;
        }
        for (int i = 8; i < 128; i += 8) {
#pragma unroll
            for (int j = 0; j < 8; ++j) {
                const float v = p[(size_t)(half * 128 + i + j) * Tt];
                const float sq = v * v;
                r[j] = r[j] + sq;
            }
        }
        h[half] = ((r[0] + r[1]) + (r[2] + r[3])) + ((r[4] + r[5]) + (r[6] + r[7]));
    }
    c[n] = h[0] + h[1];
}

__global__ void k_sumw2_np(const float* __restrict__ w, float* __restrict__ sw) {
#pragma clang fp contract(off)
    const int k = blockIdx.x * 256 + threadIdx.x;
    const float* p = w + (size_t)k * Dd;
    float h[2];
#pragma unroll
    for (int half = 0; half < 2; ++half) {
        float r[8];
#pragma unroll
        for (int j = 0; j < 8; ++j) {
            const float v = p[half * 128 + j];
            r[j] = v * v;
        }
        for (int i = 8; i < 128; i += 8) {
#pragma unroll
            for (int j = 0; j < 8; ++j) {
                const float v = p[half * 128 + i + j];
                const float sq = v * v;
                r[j] = r[j] + sq;
            }
        }
        h[half] = ((r[0] + r[1]) + (r[2] + r[3])) + ((r[4] + r[5]) + (r[6] + r[7]));
    }
    sw[k] = h[0] + h[1];
}

// ---- stage 1: bf16 MFMA filter (round-6 proven, unchanged) ----
__global__ void __launch_bounds__(512, 2)
k_mfma_filter(const short* __restrict__ xbt, const short* __restrict__ wbt,
              const float* __restrict__ sw2, float* __restrict__ cm) {
    __shared__ __align__(16) short Ws[128 * 264];
    const int tid = threadIdx.x;
    const int n0 = blockIdx.x * 128;
    const int wid = tid >> 6, lane = tid & 63;
    const int rp = wid >> 1, cp = wid & 1;
    const int l15 = lane & 15, l4 = lane >> 4;

    bf16x8 a[2][8];
#pragma unroll
    for (int rt = 0; rt < 2; ++rt)
#pragma unroll
        for (int ks = 0; ks < 8; ++ks)
            a[rt][ks] = *reinterpret_cast<const bf16x8*>(
                &xbt[(size_t)(n0 + 32 * rp + 16 * rt + l15) * Dd + 32 * ks + 8 * l4]);

    for (int c = 0; c < 64; ++c) {
#pragma unroll
        for (int m = 0; m < 8; ++m) {
            const int e = tid + 512 * m;      // 0..4095
            const int code = e >> 5, d8 = e & 31;
            *reinterpret_cast<bf16x8*>(&Ws[code * 264 + 8 * d8]) =
                *reinterpret_cast<const bf16x8*>(
                    &wbt[(size_t)(128 * c + code) * Dd + 8 * d8]);
        }
        __syncthreads();

        f32x4 acc[2][4];
#pragma unroll
        for (int rt = 0; rt < 2; ++rt)
#pragma unroll
            for (int ct = 0; ct < 4; ++ct) acc[rt][ct] = (f32x4)0.0f;

#pragma unroll
        for (int ks = 0; ks < 8; ++ks) {
            bf16x8 b[4];
#pragma unroll
            for (int ct = 0; ct < 4; ++ct)
                b[ct] = *reinterpret_cast<const bf16x8*>(
                    &Ws[(64 * cp + 16 * ct + l15) * 264 + 32 * ks + 8 * l4]);
#pragma unroll
            for (int rt = 0; rt < 2; ++rt)
#pragma unroll
                for (int ct = 0; ct < 4; ++ct)
                    acc[rt][ct] = __builtin_amdgcn_mfma_f32_16x16x32_bf16(
                        a[rt][ks], b[ct], acc[rt][ct], 0, 0, 0);
        }
        __syncthreads();

        float swc[4];
#pragma unroll
        for (int ct = 0; ct < 4; ++ct)
            swc[ct] = sw2[128 * c + 64 * cp + 16 * ct + l15];
#pragma unroll
        for (int rt = 0; rt < 2; ++rt) {
#pragma unroll
            for (int r = 0; r < 4; ++r) {
                float mm = fmaf(-2.0f, acc[rt][0][r], swc[0]);
#pragma unroll
                for (int ct = 1; ct < 4; ++ct)
                    mm = fminf(mm, fmaf(-2.0f, acc[rt][ct][r], swc[ct]));
#pragma unroll
                for (int d = 1; d < 16; d <<= 1)
                    mm = fminf(mm, __shfl_xor(mm, d));
                if (l15 == 0) {
                    const int row = n0 + 32 * rp + 16 * rt + 4 * l4 + r;
                    cm[(size_t)row * 128 + 2 * c + cp] = mm;   // [n][128], race-free
                }
            }
        }
    }
}

// ---- mask: per-row chunk mask (same floats/condition as proven select) ----
// 16 lanes per row: coalesced 512-B row reads, shuffle-reduce row min.
__global__ void __launch_bounds__(256)
k_mask(const float* __restrict__ cm, const float* __restrict__ cn,
       unsigned long long* __restrict__ mask, unsigned long long* __restrict__ keys) {
    const int tid = threadIdx.x;
    const int lane = tid & 63, w = tid >> 6;
    const int grp = lane >> 4, sub = lane & 15;
    const int n0 = blockIdx.x * 256;
    for (int pass = 0; pass < 16; ++pass) {
        const int row = n0 + pass * 16 + 4 * w + grp;
        const float4 v0 = *reinterpret_cast<const float4*>(&cm[(size_t)row * 128 + 8 * sub]);
        const float4 v1 = *reinterpret_cast<const float4*>(&cm[(size_t)row * 128 + 8 * sub + 4]);
        float gmin = fminf(fminf(fminf(v0.x, v0.y), fminf(v0.z, v0.w)),
                           fminf(fminf(v1.x, v1.y), fminf(v1.z, v1.w)));
#pragma unroll
        for (int m = 1; m < 16; m <<= 1) gmin = fminf(gmin, __shfl_xor(gmin, m));
        const float margin = 7.1e-5f + 2.6e-5f * sqrtf(cn[row]);
        const float thr = gmin + margin;
        unsigned int nib = 0;
        if (fminf(v0.x, v0.y) <= thr) nib |= 1u;   // chunk 4*sub+0
        if (fminf(v0.z, v0.w) <= thr) nib |= 2u;   // chunk 4*sub+1
        if (fminf(v1.x, v1.y) <= thr) nib |= 4u;   // chunk 4*sub+2
        if (fminf(v1.z, v1.w) <= thr) nib |= 8u;   // chunk 4*sub+3
        unsigned long long mk = (unsigned long long)nib << (4 * sub);
#pragma unroll
        for (int m = 1; m < 16; m <<= 1) mk |= __shfl_xor(mk, m);
        if (sub == 0) {
            mask[row] = mk;
            keys[row] = 0xFFFFFFFFFFFFFFFFULL;
        }
    }
}

// ---- compact: per-chunk candidate list via block prefix sum (no atomics) ----
__global__ void __launch_bounds__(1024)
k_compact(const unsigned long long* __restrict__ mask,
          unsigned int* __restrict__ cnt, unsigned short* __restrict__ lists) {
    __shared__ unsigned int sc[1024];
    const int c = blockIdx.x;
    const int t = threadIdx.x;
    const int r0 = t * 32;
    unsigned int word = 0;
#pragma unroll
    for (int j = 0; j < 32; ++j)
        word |= (unsigned int)((mask[r0 + j] >> c) & 1ULL) << j;
    const unsigned int mycnt = __popc(word);
    sc[t] = mycnt;
    __syncthreads();
    for (int off = 1; off < 1024; off <<= 1) {
        const unsigned int v = sc[t];
        const unsigned int add = (t >= off) ? sc[t - off] : 0u;
        __syncthreads();
        sc[t] = v + add;
        __syncthreads();
    }
    unsigned int base = sc[t] - mycnt;   // exclusive prefix, ascending n
    unsigned short* lc = lists + (size_t)c * Nn;
    unsigned int wrd = word;
    while (wrd) {
        const int j = __ffs(wrd) - 1;
        lc[base++] = (unsigned short)(r0 + j);
        wrd &= wrd - 1;
    }
    if (t == 1023) cnt[c] = sc[1023];
}

// ---- refine v3 (round-6 proven, unchanged) ----
#define NGB 8
__global__ void __launch_bounds__(256, 1)
k_refine(const float* __restrict__ xT, const float* __restrict__ w,
         const float* __restrict__ sw2, const float* __restrict__ cn,
         const unsigned int* __restrict__ cnt, const unsigned short* __restrict__ lists,
         unsigned long long* __restrict__ keys) {
    __shared__ __align__(16) float xs[64 * 260];   // 66.5 KB
    __shared__ __align__(16) float ws[128 * 68];   // 34.8 KB
    __shared__ float cns[64];
    __shared__ unsigned short rid_s[64];
    const int c = blockIdx.x, gb = blockIdx.y;
    const int tid = threadIdx.x;
    const int cntc = (int)cnt[c];
    const int kl = tid & 31, rg = tid >> 5;   // rg 0..7
    float swk[4];
#pragma unroll
    for (int cc = 0; cc < 4; ++cc) swk[cc] = sw2[128 * c + kl + 32 * cc];

    for (int start = gb * 64; start < cntc; start += NGB * 64) {
#pragma unroll
        for (int m = 0; m < 16; ++m) {
            const int e = tid + 256 * m;      // 0..4095
            const int j = e >> 6, d4 = e & 63;
            const int li = min(start + j, cntc - 1);
            const int row = lists[(size_t)c * Nn + li];
            *reinterpret_cast<float4*>(&xs[j * 260 + 4 * d4]) =
                *reinterpret_cast<const float4*>(&xT[(size_t)row * Dd + 4 * d4]);
        }
        if (tid < 64) {
            const int li = min(start + tid, cntc - 1);
            const unsigned short row = lists[(size_t)c * Nn + li];
            rid_s[tid] = row;
            cns[tid] = cn[row];
        }
        __syncthreads();

        float acc[8][4];
#pragma unroll
        for (int rr = 0; rr < 8; ++rr)
#pragma unroll
            for (int cc = 0; cc < 4; ++cc) acc[rr][cc] = 0.0f;

        for (int step = 0; step < 4; ++step) {
#pragma unroll
            for (int m = 0; m < 8; ++m) {
                const int e = tid + 256 * m;  // 0..2047
                const int code = e >> 4, dseg = e & 15;
                *reinterpret_cast<float4*>(&ws[code * 68 + 4 * dseg]) =
                    *reinterpret_cast<const float4*>(
                        &w[(size_t)(128 * c + code) * Dd + step * 64 + 4 * dseg]);
            }
            __syncthreads();
#pragma unroll
            for (int dl = 0; dl < 16; ++dl) {
                float4 wv[4];
#pragma unroll
                for (int cc = 0; cc < 4; ++cc)
                    wv[cc] = *reinterpret_cast<const float4*>(
                        &ws[(kl + 32 * cc) * 68 + 4 * dl]);
#pragma unroll
                for (int rr = 0; rr < 8; ++rr) {
                    const float4 xv = *reinterpret_cast<const float4*>(
                        &xs[(8 * rg + rr) * 260 + step * 64 + 4 * dl]);
#pragma unroll
                    for (int cc = 0; cc < 4; ++cc) {
                        acc[rr][cc] = fmaf(xv.x, wv[cc].x, acc[rr][cc]);
                        acc[rr][cc] = fmaf(xv.y, wv[cc].y, acc[rr][cc]);
                        acc[rr][cc] = fmaf(xv.z, wv[cc].z, acc[rr][cc]);
                        acc[rr][cc] = fmaf(xv.w, wv[cc].w, acc[rr][cc]);
                    }
                }
            }
            __syncthreads();
        }

#pragma unroll
        for (int rr = 0; rr < 8; ++rr) {
            const int rl = 8 * rg + rr;
            const float cr = cns[rl];
            float bv = 3.402823466e+38f;
            int bk = 0x7FFFFFFF;
#pragma unroll
            for (int cc = 0; cc < 4; ++cc) {
                const float t1 = cr + swk[cc];                // fl32(cn + sw)
                const float s = fmaf(-2.0f, acc[rr][cc], t1); // fl32(t1 - 2*dot)
                const int k = 128 * c + kl + 32 * cc;
                if (s < bv || (s == bv && k < bk)) { bv = s; bk = k; }
            }
#pragma unroll
            for (int d = 1; d < 32; d <<= 1) {
                const float ov = __shfl_xor(bv, d);
                const int ok = __shfl_xor(bk, d);
                if (ov < bv || (ov == bv && ok < bk)) { bv = ov; bk = ok; }
            }
            if (kl == 0) {
                const unsigned long long key =
                    ((unsigned long long)__float_as_uint(bv) << 32) |
                    (unsigned long long)(unsigned int)bk;
                atomicMin(&keys[rid_s[rl]], key);
            }
        }
        __syncthreads();
    }
}

// ---- gather + STE + partial loss (proven, key-indexed) ----
__global__ void k_quant2(const float* __restrict__ x, const float* __restrict__ w,
                         const unsigned long long* __restrict__ keys,
                         float* __restrict__ outq, float* __restrict__ idxf,
                         double* __restrict__ part) {
#pragma clang fp contract(off)
    __shared__ double red[256];
    const int tid = threadIdx.x;
    const int n0 = blockIdx.x * 64;
    const int b = n0 >> 10, t0 = n0 & 1023;
    const int tl = tid & 63;
    const int d0 = tid >> 6;
    const int n = n0 + tl;
    const int code = (int)(unsigned int)(keys[n] & 0xFFFFFFFFULL);
    if (tid < 64) idxf[n0 + tid] = (float)(int)(unsigned int)(keys[n0 + tid] & 0xFFFFFFFFULL);
    const float* wr = w + (size_t)code * Dd;
    const size_t base = (size_t)b * (Dd * Tt) + t0 + tl;
    double s = 0.0;
    for (int d = d0; d < Dd; d += 4) {
        const float xv = x[base + (size_t)d * Tt];
        const float qv = wr[d];
        const float d1 = qv - xv;
        const float qs = xv + d1;
        const float d2 = qs - xv;
        s += (double)d2 * (double)d2;
        outq[base + (size_t)d * Tt] = qs;
    }
    red[tid] = s;
    __syncthreads();
    for (int st = 128; st > 0; st >>= 1) {
        if (tid < st) red[tid] += red[tid + st];
        __syncthreads();
    }
    if (tid == 0) part[blockIdx.x] = red[0];
}

__global__ void k_loss(const double* __restrict__ part, float* __restrict__ loss) {
    __shared__ double red[512];
    const int tid = threadIdx.x;
    red[tid] = part[tid];
    __syncthreads();
    for (int st = 256; st > 0; st >>= 1) {
        if (tid < st) red[tid] += red[tid + st];
        __syncthreads();
    }
    if (tid == 0)
        loss[0] = (float)(1.25 * red[0] / (double)((size_t)Bn * Dd * Tt));
}

// ===================== LEGACY (round-2 proven) FALLBACK =====================
__global__ void k_transpose(const float* __restrict__ w, float* __restrict__ wtg) {
    __shared__ float tile[32][33];
    const int k0 = blockIdx.x * 32;
    const int d0 = blockIdx.y * 32;
    const int tx = threadIdx.x, ty = threadIdx.y;
#pragma unroll
    for (int r = 0; r < 32; r += 8)
        tile[r + ty][tx] = w[(size_t)(k0 + r + ty) * Dd + d0 + tx];
    __syncthreads();
#pragma unroll
    for (int r = 0; r < 32; r += 8)
        wtg[(size_t)(d0 + r + ty) * Kk + k0 + tx] = tile[tx][r + ty];
}

template <bool WTG>
__global__ void __launch_bounds__(512, 2)
k_argmin(const float* __restrict__ x, const float* __restrict__ w,
         const float* __restrict__ wtg, const float* __restrict__ sw2,
         const float* __restrict__ cn,
         int* __restrict__ idx_out, float* __restrict__ idx_f) {
    __shared__ __align__(16) float At[32][132];
    __shared__ __align__(16) float Wt[32][268];
    const int tid = threadIdx.x;
    const int n0 = blockIdx.x * 128;
    const int b = n0 >> 10;
    const int t0 = n0 & 1023;
    const int ty = tid >> 5;
    const int tx = tid & 31;
    const int r0 = ty * 4;
    const int c0 = tx * 4;
    const float* xb = x + (size_t)b * (Dd * Tt) + t0;

    float c8[8];
#pragma unroll
    for (int i = 0; i < 8; ++i) {
        const int row = (i < 4) ? (r0 + i) : (64 + r0 + (i - 4));
        c8[i] = cn[n0 + row];
    }
    float best[8];
    int bidx[8];
#pragma unroll
    for (int i = 0; i < 8; ++i) { best[i] = 3.402823466e+38f; bidx[i] = 0; }

    for (int kc = 0; kc < Kk; kc += 256) {
        float acc[8][8];
#pragma unroll
        for (int i = 0; i < 8; ++i)
#pragma unroll
            for (int j = 0; j < 8; ++j) acc[i][j] = 0.0f;
        for (int ds = 0; ds < Dd; ds += 32) {
#pragma unroll
            for (int u = 0; u < 2; ++u) {
                int cc = tid + 512 * u;
                int dd = cc >> 5, i4 = cc & 31;
                float4 v = *reinterpret_cast<const float4*>(
                    &xb[(size_t)(ds + dd) * Tt + i4 * 4]);
                *reinterpret_cast<float4*>(&At[dd][i4 * 4]) = v;
            }
            if (WTG) {
#pragma unroll
                for (int u = 0; u < 4; ++u) {
                    int cc = tid + 512 * u;
                    int dd = cc >> 6, j4 = cc & 63;
                    float4 v = *reinterpret_cast<const float4*>(
                        &wtg[(size_t)(ds + dd) * Kk + kc + j4 * 4]);
                    *reinterpret_cast<float4*>(&Wt[dd][j4 * 4]) = v;
                }
            } else {
#pragma unroll
                for (int u = 0; u < 4; ++u) {
                    int cc = tid + 512 * u;
                    int j = cc >> 3, m = cc & 7;
                    float4 v = *reinterpret_cast<const float4*>(
                        &w[(size_t)(kc + j) * Dd + ds + m * 4]);
                    Wt[m * 4 + 0][j] = v.x;
                    Wt[m * 4 + 1][j] = v.y;
                    Wt[m * 4 + 2][j] = v.z;
                    Wt[m * 4 + 3][j] = v.w;
                }
            }
            __syncthreads();
#pragma unroll 8
            for (int dd = 0; dd < 32; ++dd) {
                float4 a0 = *reinterpret_cast<const float4*>(&At[dd][r0]);
                float4 a1 = *reinterpret_cast<const float4*>(&At[dd][64 + r0]);
                float4 b0 = *reinterpret_cast<const float4*>(&Wt[dd][c0]);
                float4 b1 = *reinterpret_cast<const float4*>(&Wt[dd][128 + c0]);
                float av[8] = {a0.x, a0.y, a0.z, a0.w, a1.x, a1.y, a1.z, a1.w};
                float bv[8] = {b0.x, b0.y, b0.z, b0.w, b1.x, b1.y, b1.z, b1.w};
#pragma unroll
                for (int i = 0; i < 8; ++i)
#pragma unroll
                    for (int j = 0; j < 8; ++j)
                        acc[i][j] = fmaf(av[i], bv[j], acc[i][j]);
            }
            __syncthreads();
        }
#pragma unroll
        for (int j = 0; j < 8; ++j) {
            const int col = (j < 4) ? (c0 + j) : (128 + c0 + (j - 4));
            const int k = kc + col;
            const float sw = sw2[k];
#pragma unroll
            for (int i = 0; i < 8; ++i) {
                const float t1 = c8[i] + sw;
                const float s = fmaf(-2.0f, acc[i][j], t1);
                if (s < best[i] || (s == best[i] && k < bidx[i])) {
                    best[i] = s; bidx[i] = k;
                }
            }
        }
    }
#pragma unroll
    for (int i = 0; i < 8; ++i) {
        float v = best[i];
        int id = bidx[i];
#pragma unroll
        for (int m = 1; m < 32; m <<= 1) {
            const float ov = __shfl_xor(v, m);
            const int oi = __shfl_xor(id, m);
            if (ov < v || (ov == v && oi < id)) { v = ov; id = oi; }
        }
        if (tx == 0) {
            const int row = (i < 4) ? (r0 + i) : (64 + r0 + (i - 4));
            const int n = n0 + row;
            idx_out[n] = id;
            idx_f[n] = (float)id;
        }
    }
}

__global__ void k_quant(const float* __restrict__ x, const float* __restrict__ w,
                        const int* __restrict__ idx, float* __restrict__ outq,
                        double* __restrict__ part) {
#pragma clang fp contract(off)
    __shared__ double red[256];
    const int tid = threadIdx.x;
    const int n0 = blockIdx.x * 64;
    const int b = n0 >> 10, t0 = n0 & 1023;
    const int tl = tid & 63;
    const int d0 = tid >> 6;
    const int n = n0 + tl;
    const int code = idx[n];
    const float* wr = w + (size_t)code * Dd;
    const size_t base = (size_t)b * (Dd * Tt) + t0 + tl;
    double s = 0.0;
    for (int d = d0; d < Dd; d += 4) {
        const float xv = x[base + (size_t)d * Tt];
        const float qv = wr[d];
        const float d1 = qv - xv;
        const float qs = xv + d1;
        const float d2 = qs - xv;
        s += (double)d2 * (double)d2;
        outq[base + (size_t)d * Tt] = qs;
    }
    red[tid] = s;
    __syncthreads();
    for (int st = 128; st > 0; st >>= 1) {
        if (tid < st) red[tid] += red[tid + st];
        __syncthreads();
    }
    if (tid == 0) part[blockIdx.x] = red[0];
}

// ===================== host =====================
extern "C" void kernel_launch(void* const* d_in, const int* in_sizes, int n_in,
                              void* d_out, int out_size, void* d_ws, size_t ws_size,
                              hipStream_t stream) {
    const float* x = (const float*)d_in[0];
    const float* w = (const float*)d_in[1];
    float* out = (float*)d_out;
    float* loss = out;
    float* outq = out + 1;
    float* idxf = out + 1 + (size_t)Bn * Dd * Tt;
    char* ws = (char*)d_ws;

    if (ws_size >= WS_NEED) {
        float* xT = (float*)(ws + OFF_XT);
        short* xbt = (short*)(ws + OFF_XBT);
        short* wbt = (short*)(ws + OFF_WBT);
        float* cm = (float*)(ws + OFF_CM);
        unsigned long long* mask = (unsigned long long*)(ws + OFF_MASK); // aliases dead xbt
        unsigned short* lists = (unsigned short*)(ws + OFF_LIST);
        unsigned long long* keys = (unsigned long long*)(ws + OFF_KEYS);
        float* sw2 = (float*)(ws + OFF_SW2);
        float* cn = (float*)(ws + OFF_CN);
        unsigned int* cnt = (unsigned int*)(ws + OFF_CNT);
        double* part = (double*)(ws + OFF_PART);

        k_xprep<<<dim3(32, 8, 32), dim3(32, 8), 0, stream>>>(x, xT, xbt);
        k_wbf<<<(Kk * Dd) / 1024, 256, 0, stream>>>(w, wbt);
        k_sumx2_np<<<Nn / 256, 256, 0, stream>>>(x, cn);
        k_sumw2_np<<<Kk / 256, 256, 0, stream>>>(w, sw2);
        k_mfma_filter<<<Nn / 128, 512, 0, stream>>>(xbt, wbt, sw2, cm);
        k_mask<<<Nn / 256, 256, 0, stream>>>(cm, cn, mask, keys);
        k_compact<<<64, 1024, 0, stream>>>(mask, cnt, lists);
        k_refine<<<dim3(64, NGB), 256, 0, stream>>>(xT, w, sw2, cn, cnt, lists, keys);
        k_quant2<<<Nn / 64, 256, 0, stream>>>(x, w, keys, outq, idxf, part);
        k_loss<<<1, 512, 0, stream>>>(part, loss);
    } else {
        // legacy round-2 path
        float* sw2 = (float*)(ws);
        int* idx = (int*)(ws + 32768);
        double* part = (double*)(ws + 163840);
        float* cn = (float*)(ws + 172032);
        float* wtg = (float*)(ws + 524288);
        const bool use_wtg = ws_size >= (size_t)524288 + (size_t)Kk * Dd * 4;
        if (use_wtg)
            k_transpose<<<dim3(Kk / 32, Dd / 32), dim3(32, 8), 0, stream>>>(w, wtg);
        k_sumx2_np<<<Nn / 256, 256, 0, stream>>>(x, cn);
        k_sumw2_np<<<Kk / 256, 256, 0, stream>>>(w, sw2);
        if (use_wtg)
            k_argmin<true><<<Nn / 128, 512, 0, stream>>>(x, w, wtg, sw2, cn, idx, idxf);
        else
            k_argmin<false><<<Nn / 128, 512, 0, stream>>>(x, w, wtg, sw2, cn, idx, idxf);
        k_quant<<<Nn / 64, 256, 0, stream>>>(x, w, idx, outq, part);
        k_loss<<<1, 512, 0, stream>>>(part, loss);
    }
}

// Round 8
// 441.041 us; speedup vs baseline: 4.0128x; 1.1057x over previous
//
#include <hip/hip_runtime.h>
#include <hip/hip_bf16.h>

#define Bn 32
#define Dd 256
#define Tt 1024
#define Nn (Bn * Tt)   // 32768
#define Kk 8192

typedef __attribute__((ext_vector_type(8))) short bf16x8;
typedef __attribute__((ext_vector_type(4))) float f32x4;

static __device__ __forceinline__ short f2bf(float v) {
    __hip_bfloat16 h = __float2bfloat16(v);
    return *reinterpret_cast<short*>(&h);
}

// ===================== ws layout (total == proven 75927808) ====================
#define OFF_XT    0ULL            // f32 [32768][256]  32 MB
#define OFF_XBT   33554432ULL     // bf16 [32768][256] 16 MB (dead after filter -> mask reuses)
#define OFF_WBT   50331648ULL     // bf16 [8192][256]   4 MB
#define OFF_CM    54525952ULL     // f32 [32768][128]  16 MB  (chunk-min, col=2c+cp)
#define OFF_LIST  71303168ULL     // u16 [64][32768]    4 MB
#define OFF_KEYS  75497472ULL     // u64 [32768]      256 KB
#define OFF_SW2   75759616ULL     // f32 [8192]
#define OFF_CN    75792384ULL     // f32 [32768]
#define OFF_CNT   75923456ULL     // u32 [64]
#define OFF_PART  75923712ULL     // f64 [512]
#define WS_NEED   75927808ULL
#define OFF_MASK  OFF_XBT         // u64 [32768] 256 KB, aliases dead xbt

// ---- prep: x [b][d][t] -> xT f32 [n][d], xbt bf16 [n][d] ----
__global__ void k_xprep(const float* __restrict__ x, float* __restrict__ xT,
                        short* __restrict__ xbt) {
    __shared__ float tile[32][33];
    const int b = blockIdx.z, d0 = blockIdx.y * 32, t0 = blockIdx.x * 32;
    const int tx = threadIdx.x, ty = threadIdx.y;
#pragma unroll
    for (int r = 0; r < 32; r += 8)
        tile[ty + r][tx] = x[((size_t)(b * Dd + d0 + ty + r)) * Tt + t0 + tx];
    __syncthreads();
#pragma unroll
    for (int r = 0; r < 32; r += 8) {
        const size_t o = (size_t)(b * Tt + t0 + ty + r) * Dd + d0 + tx;
        const float v = tile[tx][ty + r];
        xT[o] = v;
        xbt[o] = f2bf(v);
    }
}

// ---- prep: w -> bf16 elementwise ----
__global__ void k_wbf(const float* __restrict__ w, short* __restrict__ wbt) {
    const int i = (blockIdx.x * 256 + threadIdx.x) * 4;
    const float4 v = *reinterpret_cast<const float4*>(&w[i]);
    short4 o;
    o.x = f2bf(v.x); o.y = f2bf(v.y); o.z = f2bf(v.z); o.w = f2bf(v.w);
    *reinterpret_cast<short4*>(&wbt[i]) = o;
}

// ---- numpy-pairwise-exact sum of squares (proven round 2) ----
__global__ void k_sumx2_np(const float* __restrict__ x, float* __restrict__ c) {
#pragma clang fp contract(off)
    const int n = blockIdx.x * 256 + threadIdx.x;
    const int b = n >> 10, t = n & 1023;
    const float* p = x + (size_t)b * (Dd * Tt) + t;
    float h[2];
#pragma unroll
    for (int half = 0; half < 2; ++half) {
        float r[8];
#pragma unroll
        for (int j = 0; j < 8; ++j) {
            const float v = p[(size_t)(half * 128 + j) * Tt];
            r[j] = v * v;
        }
        for (int i = 8; i < 128; i += 8) {
#pragma unroll
            for (int j = 0; j < 8; ++j) {
                const float v = p[(size_t)(half * 128 + i + j) * Tt];
                const float sq = v * v;
                r[j] = r[j] + sq;
            }
        }
        h[half] = ((r[0] + r[1]) + (r[2] + r[3])) + ((r[4] + r[5]) + (r[6] + r[7]));
    }
    c[n] = h[0] + h[1];
}

__global__ void k_sumw2_np(const float* __restrict__ w, float* __restrict__ sw) {
#pragma clang fp contract(off)
    const int k = blockIdx.x * 256 + threadIdx.x;
    const float* p = w + (size_t)k * Dd;
    float h[2];
#pragma unroll
    for (int half = 0; half < 2; ++half) {
        float r[8];
#pragma unroll
        for (int j = 0; j < 8; ++j) {
            const float v = p[half * 128 + j];
            r[j] = v * v;
        }
        for (int i = 8; i < 128; i += 8) {
#pragma unroll
            for (int j = 0; j < 8; ++j) {
                const float v = p[half * 128 + i + j];
                const float sq = v * v;
                r[j] = r[j] + sq;
            }
        }
        h[half] = ((r[0] + r[1]) + (r[2] + r[3])) + ((r[4] + r[5]) + (r[6] + r[7]));
    }
    sw[k] = h[0] + h[1];
}

// ---- stage 1: bf16 MFMA filter — chunk-halved grid for 2 blocks/CU ----
// grid (256 n-tiles, 2 chunk-halves); block does 128 rows x 32 chunks.
// A in registers; Ws 67.6 KB -> two blocks co-resident hide barrier stalls.
__global__ void __launch_bounds__(512, 4)
k_mfma_filter(const short* __restrict__ xbt, const short* __restrict__ wbt,
              const float* __restrict__ sw2, float* __restrict__ cm) {
    __shared__ __align__(16) short Ws[128 * 264];
    const int tid = threadIdx.x;
    const int n0 = blockIdx.x * 128;
    const int cbase = blockIdx.y * 32;
    const int wid = tid >> 6, lane = tid & 63;
    const int rp = wid >> 1, cp = wid & 1;
    const int l15 = lane & 15, l4 = lane >> 4;

    bf16x8 a[2][8];
#pragma unroll
    for (int rt = 0; rt < 2; ++rt)
#pragma unroll
        for (int ks = 0; ks < 8; ++ks)
            a[rt][ks] = *reinterpret_cast<const bf16x8*>(
                &xbt[(size_t)(n0 + 32 * rp + 16 * rt + l15) * Dd + 32 * ks + 8 * l4]);

    for (int cc = 0; cc < 32; ++cc) {
        const int c = cbase + cc;
#pragma unroll
        for (int m = 0; m < 8; ++m) {
            const int e = tid + 512 * m;      // 0..4095
            const int code = e >> 5, d8 = e & 31;
            *reinterpret_cast<bf16x8*>(&Ws[code * 264 + 8 * d8]) =
                *reinterpret_cast<const bf16x8*>(
                    &wbt[(size_t)(128 * c + code) * Dd + 8 * d8]);
        }
        __syncthreads();

        f32x4 acc[2][4];
#pragma unroll
        for (int rt = 0; rt < 2; ++rt)
#pragma unroll
            for (int ct = 0; ct < 4; ++ct) acc[rt][ct] = (f32x4)0.0f;

#pragma unroll
        for (int ks = 0; ks < 8; ++ks) {
            bf16x8 b[4];
#pragma unroll
            for (int ct = 0; ct < 4; ++ct)
                b[ct] = *reinterpret_cast<const bf16x8*>(
                    &Ws[(64 * cp + 16 * ct + l15) * 264 + 32 * ks + 8 * l4]);
#pragma unroll
            for (int rt = 0; rt < 2; ++rt)
#pragma unroll
                for (int ct = 0; ct < 4; ++ct)
                    acc[rt][ct] = __builtin_amdgcn_mfma_f32_16x16x32_bf16(
                        a[rt][ks], b[ct], acc[rt][ct], 0, 0, 0);
        }
        __syncthreads();   // Ws reads done; next iteration may restage

        float swc[4];
#pragma unroll
        for (int ct = 0; ct < 4; ++ct)
            swc[ct] = sw2[128 * c + 64 * cp + 16 * ct + l15];
#pragma unroll
        for (int rt = 0; rt < 2; ++rt) {
#pragma unroll
            for (int r = 0; r < 4; ++r) {
                float mm = fmaf(-2.0f, acc[rt][0][r], swc[0]);
#pragma unroll
                for (int ct = 1; ct < 4; ++ct)
                    mm = fminf(mm, fmaf(-2.0f, acc[rt][ct][r], swc[ct]));
#pragma unroll
                for (int d = 1; d < 16; d <<= 1)
                    mm = fminf(mm, __shfl_xor(mm, d));
                if (l15 == 0) {
                    const int row = n0 + 32 * rp + 16 * rt + 4 * l4 + r;
                    cm[(size_t)row * 128 + 2 * c + cp] = mm;   // [n][128], race-free
                }
            }
        }
    }
}

// ---- mask: per-row chunk mask (proven round 7) ----
__global__ void __launch_bounds__(256)
k_mask(const float* __restrict__ cm, const float* __restrict__ cn,
       unsigned long long* __restrict__ mask, unsigned long long* __restrict__ keys) {
    const int tid = threadIdx.x;
    const int lane = tid & 63, w = tid >> 6;
    const int grp = lane >> 4, sub = lane & 15;
    const int n0 = blockIdx.x * 256;
    for (int pass = 0; pass < 16; ++pass) {
        const int row = n0 + pass * 16 + 4 * w + grp;
        const float4 v0 = *reinterpret_cast<const float4*>(&cm[(size_t)row * 128 + 8 * sub]);
        const float4 v1 = *reinterpret_cast<const float4*>(&cm[(size_t)row * 128 + 8 * sub + 4]);
        float gmin = fminf(fminf(fminf(v0.x, v0.y), fminf(v0.z, v0.w)),
                           fminf(fminf(v1.x, v1.y), fminf(v1.z, v1.w)));
#pragma unroll
        for (int m = 1; m < 16; m <<= 1) gmin = fminf(gmin, __shfl_xor(gmin, m));
        const float margin = 7.1e-5f + 2.6e-5f * sqrtf(cn[row]);
        const float thr = gmin + margin;
        unsigned int nib = 0;
        if (fminf(v0.x, v0.y) <= thr) nib |= 1u;
        if (fminf(v0.z, v0.w) <= thr) nib |= 2u;
        if (fminf(v1.x, v1.y) <= thr) nib |= 4u;
        if (fminf(v1.z, v1.w) <= thr) nib |= 8u;
        unsigned long long mk = (unsigned long long)nib << (4 * sub);
#pragma unroll
        for (int m = 1; m < 16; m <<= 1) mk |= __shfl_xor(mk, m);
        if (sub == 0) {
            mask[row] = mk;
            keys[row] = 0xFFFFFFFFFFFFFFFFULL;
        }
    }
}

// ---- compact: per-chunk candidate list via block prefix sum (proven round 7) ----
__global__ void __launch_bounds__(1024)
k_compact(const unsigned long long* __restrict__ mask,
          unsigned int* __restrict__ cnt, unsigned short* __restrict__ lists) {
    __shared__ unsigned int sc[1024];
    const int c = blockIdx.x;
    const int t = threadIdx.x;
    const int r0 = t * 32;
    unsigned int word = 0;
#pragma unroll
    for (int j = 0; j < 32; ++j)
        word |= (unsigned int)((mask[r0 + j] >> c) & 1ULL) << j;
    const unsigned int mycnt = __popc(word);
    sc[t] = mycnt;
    __syncthreads();
    for (int off = 1; off < 1024; off <<= 1) {
        const unsigned int v = sc[t];
        const unsigned int add = (t >= off) ? sc[t - off] : 0u;
        __syncthreads();
        sc[t] = v + add;
        __syncthreads();
    }
    unsigned int base = sc[t] - mycnt;   // exclusive prefix, ascending n
    unsigned short* lc = lists + (size_t)c * Nn;
    unsigned int wrd = word;
    while (wrd) {
        const int j = __ffs(wrd) - 1;
        lc[base++] = (unsigned short)(r0 + j);
        wrd &= wrd - 1;
    }
    if (t == 1023) cnt[c] = sc[1023];
}

// ---- refine v3 (round-6 proven, unchanged) ----
#define NGB 8
__global__ void __launch_bounds__(256, 1)
k_refine(const float* __restrict__ xT, const float* __restrict__ w,
         const float* __restrict__ sw2, const float* __restrict__ cn,
         const unsigned int* __restrict__ cnt, const unsigned short* __restrict__ lists,
         unsigned long long* __restrict__ keys) {
    __shared__ __align__(16) float xs[64 * 260];   // 66.5 KB
    __shared__ __align__(16) float ws[128 * 68];   // 34.8 KB
    __shared__ float cns[64];
    __shared__ unsigned short rid_s[64];
    const int c = blockIdx.x, gb = blockIdx.y;
    const int tid = threadIdx.x;
    const int cntc = (int)cnt[c];
    const int kl = tid & 31, rg = tid >> 5;   // rg 0..7
    float swk[4];
#pragma unroll
    for (int cc = 0; cc < 4; ++cc) swk[cc] = sw2[128 * c + kl + 32 * cc];

    for (int start = gb * 64; start < cntc; start += NGB * 64) {
#pragma unroll
        for (int m = 0; m < 16; ++m) {
            const int e = tid + 256 * m;      // 0..4095
            const int j = e >> 6, d4 = e & 63;
            const int li = min(start + j, cntc - 1);
            const int row = lists[(size_t)c * Nn + li];
            *reinterpret_cast<float4*>(&xs[j * 260 + 4 * d4]) =
                *reinterpret_cast<const float4*>(&xT[(size_t)row * Dd + 4 * d4]);
        }
        if (tid < 64) {
            const int li = min(start + tid, cntc - 1);
            const unsigned short row = lists[(size_t)c * Nn + li];
            rid_s[tid] = row;
            cns[tid] = cn[row];
        }
        __syncthreads();

        float acc[8][4];
#pragma unroll
        for (int rr = 0; rr < 8; ++rr)
#pragma unroll
            for (int cc = 0; cc < 4; ++cc) acc[rr][cc] = 0.0f;

        for (int step = 0; step < 4; ++step) {
#pragma unroll
            for (int m = 0; m < 8; ++m) {
                const int e = tid + 256 * m;  // 0..2047
                const int code = e >> 4, dseg = e & 15;
                *reinterpret_cast<float4*>(&ws[code * 68 + 4 * dseg]) =
                    *reinterpret_cast<const float4*>(
                        &w[(size_t)(128 * c + code) * Dd + step * 64 + 4 * dseg]);
            }
            __syncthreads();
#pragma unroll
            for (int dl = 0; dl < 16; ++dl) {
                float4 wv[4];
#pragma unroll
                for (int cc = 0; cc < 4; ++cc)
                    wv[cc] = *reinterpret_cast<const float4*>(
                        &ws[(kl + 32 * cc) * 68 + 4 * dl]);
#pragma unroll
                for (int rr = 0; rr < 8; ++rr) {
                    const float4 xv = *reinterpret_cast<const float4*>(
                        &xs[(8 * rg + rr) * 260 + step * 64 + 4 * dl]);
#pragma unroll
                    for (int cc = 0; cc < 4; ++cc) {
                        acc[rr][cc] = fmaf(xv.x, wv[cc].x, acc[rr][cc]);
                        acc[rr][cc] = fmaf(xv.y, wv[cc].y, acc[rr][cc]);
                        acc[rr][cc] = fmaf(xv.z, wv[cc].z, acc[rr][cc]);
                        acc[rr][cc] = fmaf(xv.w, wv[cc].w, acc[rr][cc]);
                    }
                }
            }
            __syncthreads();
        }

#pragma unroll
        for (int rr = 0; rr < 8; ++rr) {
            const int rl = 8 * rg + rr;
            const float cr = cns[rl];
            float bv = 3.402823466e+38f;
            int bk = 0x7FFFFFFF;
#pragma unroll
            for (int cc = 0; cc < 4; ++cc) {
                const float t1 = cr + swk[cc];                // fl32(cn + sw)
                const float s = fmaf(-2.0f, acc[rr][cc], t1); // fl32(t1 - 2*dot)
                const int k = 128 * c + kl + 32 * cc;
                if (s < bv || (s == bv && k < bk)) { bv = s; bk = k; }
            }
#pragma unroll
            for (int d = 1; d < 32; d <<= 1) {
                const float ov = __shfl_xor(bv, d);
                const int ok = __shfl_xor(bk, d);
                if (ov < bv || (ov == bv && ok < bk)) { bv = ov; bk = ok; }
            }
            if (kl == 0) {
                const unsigned long long key =
                    ((unsigned long long)__float_as_uint(bv) << 32) |
                    (unsigned long long)(unsigned int)bk;
                atomicMin(&keys[rid_s[rl]], key);
            }
        }
        __syncthreads();
    }
}

// ---- gather + STE + partial loss (proven, key-indexed) ----
__global__ void k_quant2(const float* __restrict__ x, const float* __restrict__ w,
                         const unsigned long long* __restrict__ keys,
                         float* __restrict__ outq, float* __restrict__ idxf,
                         double* __restrict__ part) {
#pragma clang fp contract(off)
    __shared__ double red[256];
    const int tid = threadIdx.x;
    const int n0 = blockIdx.x * 64;
    const int b = n0 >> 10, t0 = n0 & 1023;
    const int tl = tid & 63;
    const int d0 = tid >> 6;
    const int n = n0 + tl;
    const int code = (int)(unsigned int)(keys[n] & 0xFFFFFFFFULL);
    if (tid < 64) idxf[n0 + tid] = (float)(int)(unsigned int)(keys[n0 + tid] & 0xFFFFFFFFULL);
    const float* wr = w + (size_t)code * Dd;
    const size_t base = (size_t)b * (Dd * Tt) + t0 + tl;
    double s = 0.0;
    for (int d = d0; d < Dd; d += 4) {
        const float xv = x[base + (size_t)d * Tt];
        const float qv = wr[d];
        const float d1 = qv - xv;
        const float qs = xv + d1;
        const float d2 = qs - xv;
        s += (double)d2 * (double)d2;
        outq[base + (size_t)d * Tt] = qs;
    }
    red[tid] = s;
    __syncthreads();
    for (int st = 128; st > 0; st >>= 1) {
        if (tid < st) red[tid] += red[tid + st];
        __syncthreads();
    }
    if (tid == 0) part[blockIdx.x] = red[0];
}

__global__ void k_loss(const double* __restrict__ part, float* __restrict__ loss) {
    __shared__ double red[512];
    const int tid = threadIdx.x;
    red[tid] = part[tid];
    __syncthreads();
    for (int st = 256; st > 0; st >>= 1) {
        if (tid < st) red[tid] += red[tid + st];
        __syncthreads();
    }
    if (tid == 0)
        loss[0] = (float)(1.25 * red[0] / (double)((size_t)Bn * Dd * Tt));
}

// ===================== LEGACY (round-2 proven) FALLBACK =====================
__global__ void k_transpose(const float* __restrict__ w, float* __restrict__ wtg) {
    __shared__ float tile[32][33];
    const int k0 = blockIdx.x * 32;
    const int d0 = blockIdx.y * 32;
    const int tx = threadIdx.x, ty = threadIdx.y;
#pragma unroll
    for (int r = 0; r < 32; r += 8)
        tile[r + ty][tx] = w[(size_t)(k0 + r + ty) * Dd + d0 + tx];
    __syncthreads();
#pragma unroll
    for (int r = 0; r < 32; r += 8)
        wtg[(size_t)(d0 + r + ty) * Kk + k0 + tx] = tile[tx][r + ty];
}

template <bool WTG>
__global__ void __launch_bounds__(512, 2)
k_argmin(const float* __restrict__ x, const float* __restrict__ w,
         const float* __restrict__ wtg, const float* __restrict__ sw2,
         const float* __restrict__ cn,
         int* __restrict__ idx_out, float* __restrict__ idx_f) {
    __shared__ __align__(16) float At[32][132];
    __shared__ __align__(16) float Wt[32][268];
    const int tid = threadIdx.x;
    const int n0 = blockIdx.x * 128;
    const int b = n0 >> 10;
    const int t0 = n0 & 1023;
    const int ty = tid >> 5;
    const int tx = tid & 31;
    const int r0 = ty * 4;
    const int c0 = tx * 4;
    const float* xb = x + (size_t)b * (Dd * Tt) + t0;

    float c8[8];
#pragma unroll
    for (int i = 0; i < 8; ++i) {
        const int row = (i < 4) ? (r0 + i) : (64 + r0 + (i - 4));
        c8[i] = cn[n0 + row];
    }
    float best[8];
    int bidx[8];
#pragma unroll
    for (int i = 0; i < 8; ++i) { best[i] = 3.402823466e+38f; bidx[i] = 0; }

    for (int kc = 0; kc < Kk; kc += 256) {
        float acc[8][8];
#pragma unroll
        for (int i = 0; i < 8; ++i)
#pragma unroll
            for (int j = 0; j < 8; ++j) acc[i][j] = 0.0f;
        for (int ds = 0; ds < Dd; ds += 32) {
#pragma unroll
            for (int u = 0; u < 2; ++u) {
                int cc = tid + 512 * u;
                int dd = cc >> 5, i4 = cc & 31;
                float4 v = *reinterpret_cast<const float4*>(
                    &xb[(size_t)(ds + dd) * Tt + i4 * 4]);
                *reinterpret_cast<float4*>(&At[dd][i4 * 4]) = v;
            }
            if (WTG) {
#pragma unroll
                for (int u = 0; u < 4; ++u) {
                    int cc = tid + 512 * u;
                    int dd = cc >> 6, j4 = cc & 63;
                    float4 v = *reinterpret_cast<const float4*>(
                        &wtg[(size_t)(ds + dd) * Kk + kc + j4 * 4]);
                    *reinterpret_cast<float4*>(&Wt[dd][j4 * 4]) = v;
                }
            } else {
#pragma unroll
                for (int u = 0; u < 4; ++u) {
                    int cc = tid + 512 * u;
                    int j = cc >> 3, m = cc & 7;
                    float4 v = *reinterpret_cast<const float4*>(
                        &w[(size_t)(kc + j) * Dd + ds + m * 4]);
                    Wt[m * 4 + 0][j] = v.x;
                    Wt[m * 4 + 1][j] = v.y;
                    Wt[m * 4 + 2][j] = v.z;
                    Wt[m * 4 + 3][j] = v.w;
                }
            }
            __syncthreads();
#pragma unroll 8
            for (int dd = 0; dd < 32; ++dd) {
                float4 a0 = *reinterpret_cast<const float4*>(&At[dd][r0]);
                float4 a1 = *reinterpret_cast<const float4*>(&At[dd][64 + r0]);
                float4 b0 = *reinterpret_cast<const float4*>(&Wt[dd][c0]);
                float4 b1 = *reinterpret_cast<const float4*>(&Wt[dd][128 + c0]);
                float av[8] = {a0.x, a0.y, a0.z, a0.w, a1.x, a1.y, a1.z, a1.w};
                float bv[8] = {b0.x, b0.y, b0.z, b0.w, b1.x, b1.y, b1.z, b1.w};
#pragma unroll
                for (int i = 0; i < 8; ++i)
#pragma unroll
                    for (int j = 0; j < 8; ++j)
                        acc[i][j] = fmaf(av[i], bv[j], acc[i][j]);
            }
            __syncthreads();
        }
#pragma unroll
        for (int j = 0; j < 8; ++j) {
            const int col = (j < 4) ? (c0 + j) : (128 + c0 + (j - 4));
            const int k = kc + col;
            const float sw = sw2[k];
#pragma unroll
            for (int i = 0; i < 8; ++i) {
                const float t1 = c8[i] + sw;
                const float s = fmaf(-2.0f, acc[i][j], t1);
                if (s < best[i] || (s == best[i] && k < bidx[i])) {
                    best[i] = s; bidx[i] = k;
                }
            }
        }
    }
#pragma unroll
    for (int i = 0; i < 8; ++i) {
        float v = best[i];
        int id = bidx[i];
#pragma unroll
        for (int m = 1; m < 32; m <<= 1) {
            const float ov = __shfl_xor(v, m);
            const int oi = __shfl_xor(id, m);
            if (ov < v || (ov == v && oi < id)) { v = ov; id = oi; }
        }
        if (tx == 0) {
            const int row = (i < 4) ? (r0 + i) : (64 + r0 + (i - 4));
            const int n = n0 + row;
            idx_out[n] = id;
            idx_f[n] = (float)id;
        }
    }
}

__global__ void k_quant(const float* __restrict__ x, const float* __restrict__ w,
                        const int* __restrict__ idx, float* __restrict__ outq,
                        double* __restrict__ part) {
#pragma clang fp contract(off)
    __shared__ double red[256];
    const int tid = threadIdx.x;
    const int n0 = blockIdx.x * 64;
    const int b = n0 >> 10, t0 = n0 & 1023;
    const int tl = tid & 63;
    const int d0 = tid >> 6;
    const int n = n0 + tl;
    const int code = idx[n];
    const float* wr = w + (size_t)code * Dd;
    const size_t base = (size_t)b * (Dd * Tt) + t0 + tl;
    double s = 0.0;
    for (int d = d0; d < Dd; d += 4) {
        const float xv = x[base + (size_t)d * Tt];
        const float qv = wr[d];
        const float d1 = qv - xv;
        const float qs = xv + d1;
        const float d2 = qs - xv;
        s += (double)d2 * (double)d2;
        outq[base + (size_t)d * Tt] = qs;
    }
    red[tid] = s;
    __syncthreads();
    for (int st = 128; st > 0; st >>= 1) {
        if (tid < st) red[tid] += red[tid + st];
        __syncthreads();
    }
    if (tid == 0) part[blockIdx.x] = red[0];
}

// ===================== host =====================
extern "C" void kernel_launch(void* const* d_in, const int* in_sizes, int n_in,
                              void* d_out, int out_size, void* d_ws, size_t ws_size,
                              hipStream_t stream) {
    const float* x = (const float*)d_in[0];
    const float* w = (const float*)d_in[1];
    float* out = (float*)d_out;
    float* loss = out;
    float* outq = out + 1;
    float* idxf = out + 1 + (size_t)Bn * Dd * Tt;
    char* ws = (char*)d_ws;

    if (ws_size >= WS_NEED) {
        float* xT = (float*)(ws + OFF_XT);
        short* xbt = (short*)(ws + OFF_XBT);
        short* wbt = (short*)(ws + OFF_WBT);
        float* cm = (float*)(ws + OFF_CM);
        unsigned long long* mask = (unsigned long long*)(ws + OFF_MASK); // aliases dead xbt
        unsigned short* lists = (unsigned short*)(ws + OFF_LIST);
        unsigned long long* keys = (unsigned long long*)(ws + OFF_KEYS);
        float* sw2 = (float*)(ws + OFF_SW2);
        float* cn = (float*)(ws + OFF_CN);
        unsigned int* cnt = (unsigned int*)(ws + OFF_CNT);
        double* part = (double*)(ws + OFF_PART);

        k_xprep<<<dim3(32, 8, 32), dim3(32, 8), 0, stream>>>(x, xT, xbt);
        k_wbf<<<(Kk * Dd) / 1024, 256, 0, stream>>>(w, wbt);
        k_sumx2_np<<<Nn / 256, 256, 0, stream>>>(x, cn);
        k_sumw2_np<<<Kk / 256, 256, 0, stream>>>(w, sw2);
        k_mfma_filter<<<dim3(Nn / 128, 2), 512, 0, stream>>>(xbt, wbt, sw2, cm);
        k_mask<<<Nn / 256, 256, 0, stream>>>(cm, cn, mask, keys);
        k_compact<<<64, 1024, 0, stream>>>(mask, cnt, lists);
        k_refine<<<dim3(64, NGB), 256, 0, stream>>>(xT, w, sw2, cn, cnt, lists, keys);
        k_quant2<<<Nn / 64, 256, 0, stream>>>(x, w, keys, outq, idxf, part);
        k_loss<<<1, 512, 0, stream>>>(part, loss);
    } else {
        // legacy round-2 path
        float* sw2 = (float*)(ws);
        int* idx = (int*)(ws + 32768);
        double* part = (double*)(ws + 163840);
        float* cn = (float*)(ws + 172032);
        float* wtg = (float*)(ws + 524288);
        const bool use_wtg = ws_size >= (size_t)524288 + (size_t)Kk * Dd * 4;
        if (use_wtg)
            k_transpose<<<dim3(Kk / 32, Dd / 32), dim3(32, 8), 0, stream>>>(w, wtg);
        k_sumx2_np<<<Nn / 256, 256, 0, stream>>>(x, cn);
        k_sumw2_np<<<Kk / 256, 256, 0, stream>>>(w, sw2);
        if (use_wtg)
            k_argmin<true><<<Nn / 128, 512, 0, stream>>>(x, w, wtg, sw2, cn, idx, idxf);
        else
            k_argmin<false><<<Nn / 128, 512, 0, stream>>>(x, w, wtg, sw2, cn, idx, idxf);
        k_quant<<<Nn / 64, 256, 0, stream>>>(x, w, idx, outq, part);
        k_loss<<<1, 512, 0, stream>>>(part, loss);
    }
}